// Round 3
// baseline (539.649 us; speedup 1.0000x reference)
//
#include <hip/hip_runtime.h>
#include <hip/hip_bf16.h>
#include <cmath>

typedef __hip_bfloat16 bf16;
typedef __attribute__((ext_vector_type(8))) short s16x8;
typedef __attribute__((ext_vector_type(4))) float f32x4;

#define B_   2
#define T_   2048
#define C_   2048
#define H_   16
#define HD_  128
#define RD_  64
#define QLR_ 1536
#define KLR_ 512
#define SCALE_ 0.07216878364870322f   // (128+64)^-0.5

static __device__ __forceinline__ float b2f(bf16 v){ return __bfloat162float(v); }
static __device__ __forceinline__ bf16  f2b(float v){ return __float2bfloat16(v); }
static __device__ __forceinline__ float us2f(unsigned short u){
    union { unsigned short s[2]; float f; } v; v.s[0]=0; v.s[1]=u; return v.f;
}
static __device__ __forceinline__ float ldS(const void* p, size_t i, int isf32){
    return isf32 ? ((const float*)p)[i] : b2f(((const bf16*)p)[i]);
}
static __device__ __forceinline__ void ld4(const void* p, size_t i, int isf32, float* o){
    if (isf32) {
        float4 v = *(const float4*)((const float*)p + i);
        o[0]=v.x; o[1]=v.y; o[2]=v.z; o[3]=v.w;
    } else {
        ushort4 u = *(const ushort4*)((const bf16*)p + i);
        o[0]=us2f(u.x); o[1]=us2f(u.y); o[2]=us2f(u.z); o[3]=us2f(u.w);
    }
}

// ---------------------------------------------------------------------------
// dtype detector (1 = harness buffers are f32, 0 = bf16)
// ---------------------------------------------------------------------------
__global__ __launch_bounds__(64) void detect_kernel(const unsigned short* __restrict__ x,
                                                    int* __restrict__ flag)
{
    int big = 0;
    for (int i = threadIdx.x; i < 1024; i += 64) {
        const unsigned short u = x[2*i];
        const int e = (u >> 7) & 0xFF;
        if (e >= 139) big++;
    }
    #pragma unroll
    for (int off = 32; off; off >>= 1) big += __shfl_down(big, off, 64);
    if (threadIdx.x == 0) *flag = (big > 8) ? 1 : 0;
}

// ---------------------------------------------------------------------------
// Elementwise convert harness buffer -> bf16 (8 elems/thread)
// ---------------------------------------------------------------------------
__global__ __launch_bounds__(256) void convert_kernel(const void* __restrict__ in,
                                                      bf16* __restrict__ out, int n,
                                                      const int* __restrict__ flag)
{
    const int f = *flag;
    const int i0 = (blockIdx.x * 256 + threadIdx.x) * 8;
    if (i0 >= n) return;
    float v[8];
    ld4(in, i0, f, v);
    ld4(in, i0 + 4, f, v + 4);
    bf16* o = out + i0;
    #pragma unroll
    for (int k = 0; k < 8; ++k) o[k] = f2b(v[k]);
}

// ---------------------------------------------------------------------------
// Batched transpose: several harness weights [R][Cc] -> bf16 [Cc][R].
// ---------------------------------------------------------------------------
struct TDesc { const void* in; bf16* out; int R, Cc, blkStart, nx; };
struct TBatch { TDesc d[5]; int nseg; };

__global__ __launch_bounds__(256) void transpose_batch(TBatch tb,
                                                       const int* __restrict__ flag)
{
    const int f = *flag;
    const int bid = blockIdx.x;
    int s = 0;
    #pragma unroll
    for (int i = 1; i < 5; ++i)
        if (i < tb.nseg && bid >= tb.d[i].blkStart) s = i;
    const TDesc d = tb.d[s];
    const int local = bid - d.blkStart;
    const int c0 = (local % d.nx) * 32;
    const int r0 = (local / d.nx) * 32;

    __shared__ float tile[32][33];
    const int tx = threadIdx.x & 31, ty = threadIdx.x >> 5;  // 32 x 8
    #pragma unroll
    for (int i = 0; i < 4; ++i)
        tile[ty + 8*i][tx] = ldS(d.in, (size_t)(r0 + ty + 8*i) * d.Cc + c0 + tx, f);
    __syncthreads();
    #pragma unroll
    for (int i = 0; i < 4; ++i)
        d.out[(size_t)(c0 + ty + 8*i) * d.R + r0 + tx] = f2b(tile[tx][ty + 8*i]);
}

// ---------------------------------------------------------------------------
// Transpose V half of kv [4096][4096] into vT[(b*H+h)*HD + d][t].
// ---------------------------------------------------------------------------
__global__ __launch_bounds__(256) void transpose_v_kernel(const bf16* __restrict__ kvb,
                                                          bf16* __restrict__ vT)
{
    __shared__ bf16 tile[32][34];
    const int c0 = blockIdx.x * 32;        // v-col 0..2047
    const int r0 = blockIdx.y * 32;        // row 0..4095 (b*T + t)
    const int tx = threadIdx.x & 31, ty = threadIdx.x >> 5;
    #pragma unroll
    for (int i = 0; i < 4; ++i)
        tile[ty + 8*i][tx] = kvb[(size_t)(r0 + ty + 8*i) * (H_*256) + H_*128 + c0 + tx];
    __syncthreads();
    const int b  = r0 >> 11;
    const int t0 = r0 & (T_ - 1);
    #pragma unroll
    for (int i = 0; i < 4; ++i) {
        const int c  = c0 + ty + 8*i;
        const int hh = c >> 7, dd = c & 127;
        vT[(((size_t)b*H_ + hh)*HD_ + dd)*T_ + t0 + tx] = tile[tx][ty + 8*i];
    }
}

struct GOuts { void* p[3]; int start[3]; int stride[3]; int nseg; };

// ---------------------------------------------------------------------------
// mfma_gemm (legacy 128x128, 2-phase): kept ONLY for the 64-wide k_pe tail.
// bnOff shifts the column-block origin so a (1,32) grid can cover cols
// 2048..2175 of the fused x-weight matrix.
// ---------------------------------------------------------------------------
__global__ __launch_bounds__(256) void mfma_gemm(const bf16* __restrict__ A,
                                                 const bf16* __restrict__ BT,
                                                 GOuts go, int N, int K,
                                                 const int* __restrict__ flag, int cH,
                                                 int bnOff)
{
    const int cf = cH ? *flag : 0;
    __shared__ bf16 As[128 * 32];
    __shared__ bf16 Bs[128 * 32];
    const int tid  = threadIdx.x;
    const int w    = tid >> 6;
    const int lane = tid & 63;
    const int quad = lane >> 4;
    const int l16  = lane & 15;
    const int wm   = w >> 1, wn = w & 1;
    const int bm   = blockIdx.y * 128, bn = (blockIdx.x + bnOff) * 128;
    const int lrow = lane >> 2;
    const int lk   = (lane & 3) * 8;

    int seg = 0;
    #pragma unroll
    for (int i = 1; i < 3; ++i)
        if (i < go.nseg && bn >= go.start[i]) seg = i;
    void* const dstp   = go.p[seg];
    const int  dstoff  = go.start[seg];
    const int  dstride = go.stride[seg];

    f32x4 acc[4][4];
    #pragma unroll
    for (int i = 0; i < 4; ++i)
        #pragma unroll
        for (int j = 0; j < 4; ++j)
            acc[i][j] = (f32x4){0.f, 0.f, 0.f, 0.f};

    for (int kk = 0; kk < K; kk += 32) {
        if (kk) __syncthreads();
        #pragma unroll
        for (int c = 0; c < 2; ++c) {
            const int ch  = w * 2 + c;
            const int row = ch * 16 + lrow;
            const bf16* g = A + (size_t)(bm + row) * K + kk + lk;
            __builtin_amdgcn_global_load_lds(
                (const __attribute__((address_space(1))) unsigned int*)g,
                (__attribute__((address_space(3))) unsigned int*)(As + ch * 512),
                16, 0, 0);
        }
        #pragma unroll
        for (int c = 0; c < 2; ++c) {
            const int ch  = w * 2 + c;
            const int row = ch * 16 + lrow;
            const bf16* g = BT + (size_t)(bn + row) * K + kk + lk;
            __builtin_amdgcn_global_load_lds(
                (const __attribute__((address_space(1))) unsigned int*)g,
                (__attribute__((address_space(3))) unsigned int*)(Bs + ch * 512),
                16, 0, 0);
        }
        __syncthreads();

        s16x8 af[4], bfv[4];
        #pragma unroll
        for (int i = 0; i < 4; ++i)
            af[i] = *(const s16x8*)&As[(wm*64 + i*16 + l16) * 32 + quad*8];
        #pragma unroll
        for (int j = 0; j < 4; ++j)
            bfv[j] = *(const s16x8*)&Bs[(wn*64 + j*16 + l16) * 32 + quad*8];
        #pragma unroll
        for (int i = 0; i < 4; ++i)
            #pragma unroll
            for (int j = 0; j < 4; ++j)
                acc[i][j] = __builtin_amdgcn_mfma_f32_16x16x32_bf16(af[i], bfv[j], acc[i][j], 0, 0, 0);
    }

    #pragma unroll
    for (int i = 0; i < 4; ++i) {
        const int crow = bm + wm*64 + i*16 + quad*4;
        #pragma unroll
        for (int r = 0; r < 4; ++r) {
            #pragma unroll
            for (int j = 0; j < 4; ++j) {
                const int ccol = bn + wn*64 + j*16 + l16;
                if (ccol < N) {
                    const size_t idx = (size_t)(crow + r) * dstride + (ccol - dstoff);
                    if (cf) ((float*)dstp)[idx] = acc[i][j][r];
                    else    ((bf16*)dstp)[idx] = f2b(acc[i][j][r]);
                }
            }
        }
    }
}

// ---------------------------------------------------------------------------
// gemm256: 256x256 8-phase deep-pipelined GEMM (HK-style schedule, plain HIP).
// C[M,N] = A[M,K] @ BT[N,K]^T.  Requires M%256==0, N%256==0, K%128==0,
// segment starts multiples of 256.
//  - 512 threads = 8 waves (2M x 4N); per-wave C: 128x64 (acc 8x4 f32x4)
//  - BK=64, double-buffered 128 KiB LDS via global_load_lds (16B)
//  - st_16x32 LDS swizzle: linear LDS dest + inverse-swizzled global source
//    (lane^((lane>>5&1)<<1)) + swizzled ds_read (cg ^= ((l16>>2)&1)<<1)
//  - 8 phases / 2 K-tiles; counted vmcnt(2) ONLY at phases 4 & 8; barriers
//    via raw s_barrier so loads stay in flight across them (T3+T4)
//  - s_setprio(1) around each 16-MFMA cluster (T5)
// Schedule (iter i: compute buf0=tile 2i [ph1-4], buf1=tile 2i+1 [ph5-8]):
//  ph1: LDA(b0,qm0)+LDB(b0,qn0) | stage buf1.Ah1(t2i+1) | MFMA q00
//  ph2: LDB(b0,qn1)             | stage buf1.Bh0        | MFMA q01
//  ph3: LDA(b0,qm1)             | stage buf1.Bh1        | MFMA q11
//  ph4:                          stage buf0.Ah0(t2i+2) vmcnt(2) | MFMA q10
//  ph5-8: same pattern on buf1, staging buf0.{Ah1,Bh0,Bh1}, buf1.Ah0(t2i+3),
//         vmcnt(2) at ph8.
// vmcnt(2) at ph4 publishes tile 2i+1 (staged ph8'/1/2/3) before ph5 reads;
// vmcnt(2) at ph8 publishes tile 2i+2 (staged ph4-7) before next ph1 reads.
// Tail iterations stage clamped-source garbage into never-read buffers so
// the vmcnt counts stay uniform.
// ---------------------------------------------------------------------------
__global__ __launch_bounds__(512, 2) void gemm256(const bf16* __restrict__ A,
                                                  const bf16* __restrict__ BT,
                                                  GOuts go, int N, int K,
                                                  const int* __restrict__ flag, int cH)
{
    extern __shared__ __align__(16) char smem[];
    const int cf   = cH ? *flag : 0;
    const int tid  = threadIdx.x;
    const int lane = tid & 63;
    const int quad = lane >> 4;
    const int l16  = lane & 15;
    const int wid  = tid >> 6;
    const int wm   = wid >> 2, wn = wid & 3;
    const int bm   = blockIdx.y * 256, bn = blockIdx.x * 256;

    int seg = 0;
    #pragma unroll
    for (int i = 1; i < 3; ++i)
        if (i < go.nseg && bn >= go.start[i]) seg = i;
    void* const dstp   = go.p[seg];
    const int  dstoff  = go.start[seg];
    const int  dstride = go.stride[seg];

    const int nkt = K >> 6;      // K-tiles of 64
    const int nit = nkt >> 1;    // 2 tiles per iteration

    // staging: inverse-swizzled global source, linear LDS dest
    const int sl   = lane ^ (((lane >> 5) & 1) << 1);
    const int sCol = (sl & 7) * 8;          // bf16 col offset within BK
    const int sR   = tid >> 3;              // row within 64-row group
    // ds_read swizzle key
    const int s2   = ((l16 >> 2) & 1) << 1;
    const int cq   = quad ^ s2;
    const int aBase = wm*16384 + l16*128 + cq*16;
    const int bBase = 32768 + (wn>>1)*16384 + ((wn&1)*64 + l16)*128 + cq*16;

    f32x4 acc[8][4];
    #pragma unroll
    for (int i = 0; i < 8; ++i)
        #pragma unroll
        for (int j = 0; j < 4; ++j)
            acc[i][j] = (f32x4){0.f,0.f,0.f,0.f};

    s16x8 ar[4][2];       // current A quadrant frags [m][ks]
    s16x8 br[2][2][2];    // B frags [qn][n][ks]

    #define STG(op, buf, half, kt) do {                                          \
        const int ktc_ = ((kt) < nkt ? (kt) : nkt-1);                            \
        const bf16* base_ = (op) ? BT : A;                                       \
        const int rb_ = ((op) ? bn : bm) + (half)*128;                           \
        char* ld_ = smem + (buf)*65536 + (op)*32768 + (half)*16384;              \
        _Pragma("unroll")                                                        \
        for (int j_ = 0; j_ < 2; ++j_) {                                         \
            const bf16* g_ = base_ + (size_t)(rb_ + j_*64 + sR) * K              \
                             + ktc_*64 + sCol;                                   \
            __builtin_amdgcn_global_load_lds(                                    \
                (const __attribute__((address_space(1))) unsigned int*)g_,       \
                (__attribute__((address_space(3))) unsigned int*)(ld_ + j_*8192 + tid*16), \
                16, 0, 0);                                                       \
        }                                                                        \
    } while (0)

    #define LDA(buf, qm) do {                                                    \
        _Pragma("unroll")                                                        \
        for (int mm_ = 0; mm_ < 4; ++mm_)                                        \
            _Pragma("unroll")                                                    \
            for (int ks_ = 0; ks_ < 2; ++ks_)                                    \
                ar[mm_][ks_] = *(const s16x8*)(smem + (buf)*65536 + aBase        \
                                               + ((qm)*4+mm_)*2048 + ks_*64);    \
    } while (0)

    #define LDB(buf, qn) do {                                                    \
        _Pragma("unroll")                                                        \
        for (int nn_ = 0; nn_ < 2; ++nn_)                                        \
            _Pragma("unroll")                                                    \
            for (int ks_ = 0; ks_ < 2; ++ks_)                                    \
                br[qn][nn_][ks_] = *(const s16x8*)(smem + (buf)*65536 + bBase    \
                                               + ((qn)*2+nn_)*2048 + ks_*64);    \
    } while (0)

    #define MM(qm, qn) do {                                                      \
        __builtin_amdgcn_s_setprio(1);                                           \
        _Pragma("unroll")                                                        \
        for (int mm_ = 0; mm_ < 4; ++mm_)                                        \
            _Pragma("unroll")                                                    \
            for (int nn_ = 0; nn_ < 2; ++nn_)                                    \
                _Pragma("unroll")                                                \
                for (int ks_ = 0; ks_ < 2; ++ks_)                                \
                    acc[(qm)*4+mm_][(qn)*2+nn_] =                                \
                        __builtin_amdgcn_mfma_f32_16x16x32_bf16(                 \
                            ar[mm_][ks_], br[qn][nn_][ks_],                      \
                            acc[(qm)*4+mm_][(qn)*2+nn_], 0, 0, 0);               \
        __builtin_amdgcn_s_setprio(0);                                           \
    } while (0)

    #define BARR __builtin_amdgcn_s_barrier()
    #define VMC(n) asm volatile("s_waitcnt vmcnt(" #n ")" ::: "memory")

    // prologue: tile0 fully into buf0, tile1.Ah0 into buf1
    STG(0,0,0, 0); STG(0,0,1, 0); STG(1,0,0, 0); STG(1,0,1, 0);
    STG(0,1,0, 1);
    VMC(0); BARR;

    for (int i = 0; i < nit; ++i) {
        const int tB = 2*i + 1;   // buf1's tile (finishing its staging)
        const int tA = 2*i + 2;   // buf0's next tile
        const int tC = 2*i + 3;   // buf1's next tile (first half-tile)

        // ph1
        LDA(0,0); LDB(0,0); STG(0,1,1, tB); BARR; MM(0,0); BARR;
        // ph2
        LDB(0,1);           STG(1,1,0, tB); BARR; MM(0,1); BARR;
        // ph3
        LDA(0,1);           STG(1,1,1, tB); BARR; MM(1,1); BARR;
        // ph4
        STG(0,0,0, tA); VMC(2); BARR; MM(1,0); BARR;
        // ph5
        LDA(1,0); LDB(1,0); STG(0,0,1, tA); BARR; MM(0,0); BARR;
        // ph6
        LDB(1,1);           STG(1,0,0, tA); BARR; MM(0,1); BARR;
        // ph7
        LDA(1,1);           STG(1,0,1, tA); BARR; MM(1,1); BARR;
        // ph8
        STG(0,1,0, tC); VMC(2); BARR; MM(1,0); BARR;
    }

    VMC(0);

    #undef STG
    #undef LDA
    #undef LDB
    #undef MM
    #undef BARR
    #undef VMC

    #pragma unroll
    for (int mm = 0; mm < 8; ++mm) {
        const int crow = bm + wm*128 + mm*16 + quad*4;
        #pragma unroll
        for (int r = 0; r < 4; ++r) {
            #pragma unroll
            for (int nn = 0; nn < 4; ++nn) {
                const int ccol = bn + wn*64 + nn*16 + l16;
                const size_t idx = (size_t)(crow + r) * dstride + (ccol - dstoff);
                if (cf) ((float*)dstp)[idx] = acc[mm][nn][r];
                else    ((bf16*)dstp)[idx] = f2b(acc[mm][nn][r]);
            }
        }
    }
}

// ---------------------------------------------------------------------------
// In-place RMSNorm over rows of X [rows, NPER*256] (internal bf16)
// ---------------------------------------------------------------------------
template<int NPER>
__global__ __launch_bounds__(256) void rms_kernel(bf16* __restrict__ X,
                                                  const void* __restrict__ w,
                                                  const int* __restrict__ flag)
{
    const int wf = *flag;
    const int ncols = NPER * 256;
    __shared__ float red[4];
    const int row = blockIdx.x;
    const int tid = threadIdx.x;
    bf16* xr = X + (size_t)row * ncols;
    float vals[NPER];
    float ss = 0.f;
    #pragma unroll
    for (int i = 0; i < NPER; ++i) {
        float v = b2f(xr[tid + i*256]);
        vals[i] = v; ss += v*v;
    }
    #pragma unroll
    for (int off = 32; off; off >>= 1) ss += __shfl_down(ss, off, 64);
    if ((tid & 63) == 0) red[tid >> 6] = ss;
    __syncthreads();
    const float tot = red[0]+red[1]+red[2]+red[3];
    const float rs  = rsqrtf(tot / (float)ncols + 1e-6f);
    #pragma unroll
    for (int i = 0; i < NPER; ++i) {
        const int c = tid + i*256;
        xr[c] = f2b(vals[i] * rs * ldS(w, c, wf));
    }
}

// ---------------------------------------------------------------------------
// k_pe: in-place RMSNorm over 64 cols + RoPE
// ---------------------------------------------------------------------------
__global__ __launch_bounds__(64) void kpe_rms_rope(bf16* __restrict__ X,
                                                   const void* __restrict__ w,
                                                   const int* __restrict__ flag)
{
    const int wf   = *flag;
    const int row  = blockIdx.x;
    const int t    = row & (T_ - 1);
    const int lane = threadIdx.x;
    bf16* xr = X + (size_t)row * RD_;
    const float v = b2f(xr[lane]);
    float ss = v * v;
    #pragma unroll
    for (int off = 32; off; off >>= 1) ss += __shfl_down(ss, off, 64);
    ss = __shfl(ss, 0, 64);
    const float rs = rsqrtf(ss / 64.f + 1e-6f);
    const float xn = v * rs * ldS(w, lane, wf);
    const int   i  = lane & 31;
    const float freq = powf(10000.f, -(float)(2*i) / 64.f);
    const float ang  = (float)t * freq;
    const float s = sinf(ang), c = cosf(ang);
    const float other = __shfl_xor(xn, 32, 64);
    const float o = (lane < 32) ? (xn * c - other * s) : (other * s + xn * c);
    xr[lane] = f2b(o);
}

// ---------------------------------------------------------------------------
// q_pe RoPE in-place: X [B*T, H*64]
// ---------------------------------------------------------------------------
__global__ __launch_bounds__(256) void qpe_rope(bf16* __restrict__ X)
{
    const int row = blockIdx.x;
    const int t   = row & (T_ - 1);
    bf16* xr = X + (size_t)row * (H_ * RD_);
    const int tid = threadIdx.x;
    #pragma unroll
    for (int pp = 0; pp < 2; ++pp) {
        const int p  = tid + pp * 256;
        const int hh = p >> 5;
        const int i  = p & 31;
        const int i0 = hh * 64 + i;
        const int i1 = i0 + 32;
        const float x1 = b2f(xr[i0]), x2 = b2f(xr[i1]);
        const float freq = powf(10000.f, -(float)(2*i) / 64.f);
        const float ang  = (float)t * freq;
        const float s = sinf(ang), c = cosf(ang);
        xr[i0] = f2b(x1 * c - x2 * s);
        xr[i1] = f2b(x1 * s + x2 * c);
    }
}

// ---------------------------------------------------------------------------
// Flash-style MFMA attention v5 (passing @114.5us, round-2 verified):
// tight LDS + XOR swizzle (48KB, 3 blocks/CU), spill-free softmax.
// ---------------------------------------------------------------------------
__global__ __launch_bounds__(256, 2) void flash_attn(const bf16* __restrict__ qnop,
                                                     const bf16* __restrict__ qpe,
                                                     const bf16* __restrict__ kv,
                                                     const bf16* __restrict__ kpe,
                                                     const bf16* __restrict__ vT,
                                                     bf16* __restrict__ y)
{
    __shared__ __align__(16) short Klds[64 * 192];
    __shared__ __align__(16) short Vt[128 * 64];
    __shared__ __align__(16) short Plds[4][16 * 64];

    const int h   = blockIdx.x;
    const int qt  = 31 - (int)blockIdx.y;          // heavy blocks dispatched first
    const int b   = blockIdx.z;
    const int q0  = qt * 64;
    const int tid = threadIdx.x;
    const int w    = tid >> 6;
    const int lane = tid & 63;
    const int quad = lane >> 4;
    const int l16  = lane & 15;
    const int rk   = l16 & 7;
    const int rkp  = (l16 ^ (l16 >> 3)) & 7;
    const int row0 = q0 + w * 16;
    const size_t bT = (size_t)b * T_;
    const int bh  = b * H_ + h;

    const int kR = tid >> 4, kS = tid & 15;
    const int pR = tid >> 3, pS = tid & 7;
    const int vD = tid >> 3, vS = tid & 7;

    const bf16* gK = kv  + (bT + kR) * (H_*256) + h*128 + kS*8;
    const bf16* gP = kpe + (bT + pR) * RD_ + pS*8;
    const bf16* gV = vT  + ((size_t)bh*HD_ + vD) * T_ + vS*8;

    short* const wK = &Klds[kR*192 + ((kS ^ (kR & 7)) << 3)];
    short* const wP = &Klds[pR*192 + 128 + ((pS ^ (pR & 7)) << 3)];
    short* const wV = &Vt[vD*64 + ((vS ^ (vD & 7)) << 3)];

    s16x8 aq[6];
    {
        const size_t r = bT + row0 + l16;
        const bf16* qn = qnop + r * (H_*128) + h*128 + quad*8;
        #pragma unroll
        for (int kk = 0; kk < 4; ++kk) aq[kk] = *(const s16x8*)(qn + kk*32);
        const bf16* qp = qpe + r * (H_*64) + h*64 + quad*8;
        aq[4] = *(const s16x8*)(qp);
        aq[5] = *(const s16x8*)(qp + 32);
    }

    f32x4 o[8];
    #pragma unroll
    for (int i = 0; i < 8; ++i) o[i] = (f32x4){0.f,0.f,0.f,0.f};
    float m_run[4] = {-1e30f,-1e30f,-1e30f,-1e30f};
    float l_run[4] = {0.f,0.f,0.f,0.f};

    uint4 k0, k1, k2, k3, p0, p1, v0, v1, v2, v3;
    #define PF(J0) do {                                                     \
        const bf16* a_ = gK + (size_t)(J0) * (H_*256);                      \
        k0 = *(const uint4*)(a_);                                           \
        k1 = *(const uint4*)(a_ + 16*(H_*256));                             \
        k2 = *(const uint4*)(a_ + 32*(H_*256));                             \
        k3 = *(const uint4*)(a_ + 48*(H_*256));                             \
        const bf16* p_ = gP + (size_t)(J0) * RD_;                           \
        p0 = *(const uint4*)(p_);                                           \
        p1 = *(const uint4*)(p_ + 32*RD_);                                  \
        const bf16* v_ = gV + (J0);                                         \
        v0 = *(const uint4*)(v_);                                           \
        v1 = *(const uint4*)(v_ + 32*T_);                                   \
        v2 = *(const uint4*)(v_ + 64*T_);                                   \
        v3 = *(const uint4*)(v_ + 96*T_);                                   \
    } while (0)

    PF(0);

    const int ntiles = qt + 1;
    for (int it = 0; it < ntiles; ++it) {
        const int j0 = it * 64;
        asm volatile("s_waitcnt lgkmcnt(0)\n\ts_barrier" ::: "memory");

        *(uint4*)(wK)          = k0;
        *(uint4*)(wK + 16*192) = k1;
        *(uint4*)(wK + 32*192) = k2;
        *(uint4*)(wK + 48*192) = k3;
        *(uint4*)(wP)          = p0;
        *(uint4*)(wP + 32*192) = p1;
        *(uint4*)(wV)          = v0;
        *(uint4*)(wV + 32*64)  = v1;
        *(uint4*)(wV + 64*64)  = v2;
        *(uint4*)(wV + 96*64)  = v3;

        if (it + 1 < ntiles) PF(j0 + 64);

        asm volatile("s_waitcnt lgkmcnt(0)\n\ts_barrier" ::: "memory");

        if (j0 <= row0 + 15) {
            const bool needmask = (j0 + 63 > row0);
            f32x4 s[4];
            #pragma unroll
            for (int nsub = 0; nsub < 4; ++nsub) {
                f32x4 acc = (f32x4){0.f,0.f,0.f,0.f};
                #pragma unroll
                for (int kk = 0; kk < 6; ++kk) {
                    const s16x8 bk = *(const s16x8*)&Klds[(nsub*16 + l16)*192
                                        + ((((kk << 2) | quad) ^ rk) << 3)];
                    acc = __builtin_amdgcn_mfma_f32_16x16x32_bf16(aq[kk], bk, acc, 0, 0, 0);
                }
                #pragma unroll
                for (int reg = 0; reg < 4; ++reg) acc[reg] *= SCALE_;
                s[nsub] = acc;
            }
            if (needmask) {
                #pragma unroll
                for (int nsub = 0; nsub < 4; ++nsub)
                    #pragma unroll
                    for (int reg = 0; reg < 4; ++reg) {
                        const int col = j0 + nsub*16 + l16;
                        const int row = row0 + quad*4 + reg;
                        if (col > row) s[nsub][reg] = -1e30f;
                    }
            }
            float mt[4], alpha[4], rs[4];
            #pragma unroll
            for (int reg = 0; reg < 4; ++reg)
                mt[reg] = fmaxf(fmaxf(s[0][reg], s[1][reg]), fmaxf(s[2][reg], s[3][reg]));
            #pragma unroll
            for (int d = 1; d < 16; d <<= 1)
                #pragma unroll
                for (int reg = 0; reg < 4; ++reg)
                    mt[reg] = fmaxf(mt[reg], __shfl_xor(mt[reg], d, 64));
            #pragma unroll
            for (int reg = 0; reg < 4; ++reg) {
                const float mnew = fmaxf(m_run[reg], mt[reg]);
                alpha[reg] = __expf(m_run[reg] - mnew);
                m_run[reg] = mnew;
                rs[reg] = 0.f;
            }
            #pragma unroll
            for (int nsub = 0; nsub < 4; ++nsub)
                #pragma unroll
                for (int reg = 0; reg < 4; ++reg) {
                    const float p = __expf(s[nsub][reg] - m_run[reg]);
                    s[nsub][reg] = p;
                    rs[reg] += p;
                }
            #pragma unroll
            for (int d = 1; d < 16; d <<= 1)
                #pragma unroll
                for (int reg = 0; reg < 4; ++reg)
                    rs[reg] += __shfl_xor(rs[reg], d, 64);
            #pragma unroll
            for (int reg = 0; reg < 4; ++reg)
                l_run[reg] = l_run[reg] * alpha[reg] + rs[reg];

            #pragma unroll
            for (int nsub = 0; nsub < 4; ++nsub)
                #pragma unroll
                for (int reg = 0; reg < 4; ++reg) {
                    const bf16 pv = f2b(s[nsub][reg]);
                    const int prow = (quad << 2) + reg;
                    const int pk   = (prow ^ (prow >> 3)) & 7;
                    const int pby  = ((nsub << 5) + (l16 << 1)) ^ (pk << 4);
                    Plds[w][prow*64 + (pby >> 1)] = *(const short*)&pv;
                }
            #pragma unroll
            for (int n2 = 0; n2 < 8; ++n2)
                #pragma unroll
                for (int reg = 0; reg < 4; ++reg)
                    o[n2][reg] *= alpha[reg];

            const s16x8 ap0 = *(const s16x8*)&Plds[w][l16*64 + (((quad    ) ^ rkp) << 3)];
            const s16x8 ap1 = *(const s16x8*)&Plds[w][l16*64 + (((quad | 4) ^ rkp) << 3)];
            #pragma unroll
            for (int n2 = 0; n2 < 8; ++n2) {
                const s16x8 bv0 = *(const s16x8*)&Vt[(n2*16 + l16)*64 + (((quad    ) ^ rk) << 3)];
                const s16x8 bv1 = *(const s16x8*)&Vt[(n2*16 + l16)*64 + (((quad | 4) ^ rk) << 3)];
                o[n2] = __builtin_amdgcn_mfma_f32_16x16x32_bf16(ap0, bv0, o[n2], 0, 0, 0);
                o[n2] = __builtin_amdgcn_mfma_f32_16x16x32_bf16(ap1, bv1, o[n2], 0, 0, 0);
            }
        }
    }
    #undef PF

    #pragma unroll
    for (int reg = 0; reg < 4; ++reg) {
        const float inv = 1.f / l_run[reg];
        const size_t r = bT + row0 + quad*4 + reg;
        bf16* yr = y + r * (H_*128) + h*128 + l16;
        #pragma unroll
        for (int n2 = 0; n2 < 8; ++n2)
            yr[n2*16] = f2b(o[n2][reg] * inv);
    }
}

// ---------------------------------------------------------------------------
extern "C" void kernel_launch(void* const* d_in, const int* in_sizes, int n_in,
                              void* d_out, int out_size, void* d_ws, size_t ws_size,
                              hipStream_t stream)
{
    const void* x         = d_in[0];
    const void* Wq_down   = d_in[1];
    const void* q_norm_w  = d_in[2];
    const void* Wq_up     = d_in[3];
    const void* Wq_pe     = d_in[4];
    const void* Wkv_down  = d_in[5];
    const void* kv_norm_w = d_in[6];
    const void* Wkv_up    = d_in[7];
    const void* Wk_pe     = d_in[8];
    const void* kpe_nw    = d_in[9];
    const void* Wo        = d_in[10];

    char* ws = (char*)d_ws;
    int*  flag = (int*)(ws + 0);
    bf16* xb   = (bf16*)(ws + 256);        // [4096,2048] — dead after x-GEMM; reused as vT
    bf16* cQ   = (bf16*)(ws + 16777472);   // [4096,1536] — dead after q-GEMM; reused as P3/P4
    bf16* cKV  = (bf16*)(ws + 29360384);   // [4096, 512]
    bf16* kpeb = (bf16*)(ws + 33554688);   // [4096,  64]
    bf16* qnop = (bf16*)(ws + 34078976);   // [4096,2048]
    bf16* qpeb = (bf16*)(ws + 50856192);   // [4096,1024]
    bf16* kvb  = (bf16*)(ws + 59244800);   // [4096,4096] — written late; holds P1/P2 early
    bf16* yb   = (bf16*)(ws + 92799232);   // [4096,2048]  (end 109,576,448)

    // weight arenas (lifetime-safe overlays):
    bf16* P1 = kvb;                            // [2176][2048] x-weights^T (8.9 MB)
    bf16* P2 = (bf16*)((char*)kvb + 8912896);  // [3072][1536] q-weights^T (9.4 MB)
    bf16* P3 = cQ;                             // [4096][512]  Wkv_up^T    (4.2 MB)
    bf16* P4 = (bf16*)((char*)cQ + 4194304);   // [2048][2048] Wo^T        (8.4 MB)
    bf16* vT = xb;                             // [B*H][128][2048] V^T

    const dim3 blk(256);
    const dim3 blk512(512);

    static int attr_set = 0;
    if (!attr_set) {
        hipFuncSetAttribute(reinterpret_cast<const void*>(gemm256),
                            hipFuncAttributeMaxDynamicSharedMemorySize, 131072);
        attr_set = 1;
    }

    detect_kernel<<<1, dim3(64), 0, stream>>>((const unsigned short*)x, flag);
    convert_kernel<<<(B_*T_*C_)/(256*8), blk, 0, stream>>>(x, xb, B_*T_*C_, flag);

    // ---- batched transpose #1: x-path + q-path weights ----
    {
        TBatch tb;
        tb.d[0] = { Wq_down,  P1,               C_,  QLR_,     0, QLR_/32 };    // 3072 blks
        tb.d[1] = { Wkv_down, P1 + 1536*2048,   C_,  KLR_,  3072, KLR_/32 };    // 1024
        tb.d[2] = { Wk_pe,    P1 + 2048*2048,   C_,  RD_,   4096, RD_/32  };    //  128
        tb.d[3] = { Wq_up,    P2,               QLR_, 2048, 4224, 2048/32 };    // 3072
        tb.d[4] = { Wq_pe,    P2 + 2048*1536,   QLR_, 1024, 7296, 1024/32 };    // 1536
        tb.nseg = 5;
        transpose_batch<<<8832, blk, 0, stream>>>(tb, flag);
    }

    // ---- x-projection: cQ|cKV via gemm256 (N=2048), k_pe tail via legacy ----
    {
        GOuts go; go.nseg = 2;
        go.p[0]=cQ;   go.start[0]=0;    go.stride[0]=QLR_;
        go.p[1]=cKV;  go.start[1]=1536; go.stride[1]=KLR_;
        go.p[2]=nullptr; go.start[2]=0; go.stride[2]=0;
        gemm256<<<dim3(8, 16), blk512, 131072, stream>>>(xb, P1, go, 2048, C_, flag, 0);
    }
    {
        GOuts go; go.nseg = 1;
        go.p[0]=kpeb; go.start[0]=2048; go.stride[0]=RD_;
        go.p[1]=nullptr; go.start[1]=0; go.stride[1]=0;
        go.p[2]=nullptr; go.start[2]=0; go.stride[2]=0;
        mfma_gemm<<<dim3(1, 32), blk, 0, stream>>>(xb, P1, go, 2112, C_, flag, 0, 16);
    }
    rms_kernel<6><<<B_*T_, blk, 0, stream>>>(cQ, q_norm_w, flag);
    rms_kernel<2><<<B_*T_, blk, 0, stream>>>(cKV, kv_norm_w, flag);
    kpe_rms_rope<<<B_*T_, dim3(64), 0, stream>>>(kpeb, kpe_nw, flag);

    // ---- fused q-projection GEMM: cQ @ [Wq_up | Wq_pe] ----
    {
        GOuts go; go.nseg = 2;
        go.p[0]=qnop; go.start[0]=0;    go.stride[0]=H_*HD_;
        go.p[1]=qpeb; go.start[1]=2048; go.stride[1]=H_*RD_;
        go.p[2]=nullptr; go.start[2]=0; go.stride[2]=0;
        gemm256<<<dim3(12, 16), blk512, 131072, stream>>>(cQ, P2, go, 3072, QLR_, flag, 0);
    }
    qpe_rope<<<B_*T_, blk, 0, stream>>>(qpeb);

    // ---- batched transpose #2: Wkv_up, Wo (cQ now dead) ----
    {
        TBatch tb;
        tb.d[0] = { Wkv_up, P3, KLR_, H_*2*HD_,    0, (H_*2*HD_)/32 };  // 2048 blks
        tb.d[1] = { Wo,     P4, H_*HD_, C_,     2048, C_/32 };          // 4096
        tb.d[2] = tb.d[1]; tb.d[3] = tb.d[1]; tb.d[4] = tb.d[1];
        tb.nseg = 2;
        transpose_batch<<<6144, blk, 0, stream>>>(tb, flag);
    }

    // ---- kv up-projection, then V transpose (xb dead) ----
    {
        GOuts go; go.nseg = 1;
        go.p[0]=kvb; go.start[0]=0; go.stride[0]=H_*2*HD_;
        go.p[1]=nullptr; go.start[1]=0; go.stride[1]=0;
        go.p[2]=nullptr; go.start[2]=0; go.stride[2]=0;
        gemm256<<<dim3(16, 16), blk512, 131072, stream>>>(cKV, P3, go, H_*2*HD_, KLR_, flag, 0);
    }
    transpose_v_kernel<<<dim3((H_*HD_)/32, (B_*T_)/32), blk, 0, stream>>>(kvb, vT);

    // ---- attention ----
    flash_attn<<<dim3(H_, T_/64, B_), blk, 0, stream>>>(qnop, qpeb, kvb, kpeb, vT, yb);

    // ---- output projection (dtype of d_out per flag) ----
    {
        GOuts go; go.nseg = 1;
        go.p[0]=d_out; go.start[0]=0; go.stride[0]=C_;
        go.p[1]=nullptr; go.start[1]=0; go.stride[1]=0;
        go.p[2]=nullptr; go.start[2]=0; go.stride[2]=0;
        gemm256<<<dim3(8, 16), blk512, 131072, stream>>>(yb, P4, go, C_, H_*HD_, flag, 1);
    }
}

// Round 4
// 520.447 us; speedup vs baseline: 1.0369x; 1.0369x over previous
//
#include <hip/hip_runtime.h>
#include <hip/hip_bf16.h>
#include <cmath>

typedef __hip_bfloat16 bf16;
typedef __attribute__((ext_vector_type(8))) short s16x8;
typedef __attribute__((ext_vector_type(4))) float f32x4;

#define B_   2
#define T_   2048
#define C_   2048
#define H_   16
#define HD_  128
#define RD_  64
#define QLR_ 1536
#define KLR_ 512
#define SCALE_ 0.07216878364870322f   // (128+64)^-0.5

static __device__ __forceinline__ float b2f(bf16 v){ return __bfloat162float(v); }
static __device__ __forceinline__ bf16  f2b(float v){ return __float2bfloat16(v); }
static __device__ __forceinline__ float us2f(unsigned short u){
    union { unsigned short s[2]; float f; } v; v.s[0]=0; v.s[1]=u; return v.f;
}
static __device__ __forceinline__ float ldS(const void* p, size_t i, int isf32){
    return isf32 ? ((const float*)p)[i] : b2f(((const bf16*)p)[i]);
}
static __device__ __forceinline__ void ld4(const void* p, size_t i, int isf32, float* o){
    if (isf32) {
        float4 v = *(const float4*)((const float*)p + i);
        o[0]=v.x; o[1]=v.y; o[2]=v.z; o[3]=v.w;
    } else {
        ushort4 u = *(const ushort4*)((const bf16*)p + i);
        o[0]=us2f(u.x); o[1]=us2f(u.y); o[2]=us2f(u.z); o[3]=us2f(u.w);
    }
}

// ---------------------------------------------------------------------------
// dtype detector (1 = harness buffers are f32, 0 = bf16)
// ---------------------------------------------------------------------------
__global__ __launch_bounds__(64) void detect_kernel(const unsigned short* __restrict__ x,
                                                    int* __restrict__ flag)
{
    int big = 0;
    for (int i = threadIdx.x; i < 1024; i += 64) {
        const unsigned short u = x[2*i];
        const int e = (u >> 7) & 0xFF;
        if (e >= 139) big++;
    }
    #pragma unroll
    for (int off = 32; off; off >>= 1) big += __shfl_down(big, off, 64);
    if (threadIdx.x == 0) *flag = (big > 8) ? 1 : 0;
}

// ---------------------------------------------------------------------------
// Elementwise convert harness buffer -> bf16 (8 elems/thread)
// ---------------------------------------------------------------------------
__global__ __launch_bounds__(256) void convert_kernel(const void* __restrict__ in,
                                                      bf16* __restrict__ out, int n,
                                                      const int* __restrict__ flag)
{
    const int f = *flag;
    const int i0 = (blockIdx.x * 256 + threadIdx.x) * 8;
    if (i0 >= n) return;
    float v[8];
    ld4(in, i0, f, v);
    ld4(in, i0 + 4, f, v + 4);
    bf16* o = out + i0;
    #pragma unroll
    for (int k = 0; k < 8; ++k) o[k] = f2b(v[k]);
}

// ---------------------------------------------------------------------------
// Batched transpose: several harness weights [R][Cc] -> bf16 [Cc][R].
// ---------------------------------------------------------------------------
struct TDesc { const void* in; bf16* out; int R, Cc, blkStart, nx; };
struct TBatch { TDesc d[5]; int nseg; };

__global__ __launch_bounds__(256) void transpose_batch(TBatch tb,
                                                       const int* __restrict__ flag)
{
    const int f = *flag;
    const int bid = blockIdx.x;
    int s = 0;
    #pragma unroll
    for (int i = 1; i < 5; ++i)
        if (i < tb.nseg && bid >= tb.d[i].blkStart) s = i;
    const TDesc d = tb.d[s];
    const int local = bid - d.blkStart;
    const int c0 = (local % d.nx) * 32;
    const int r0 = (local / d.nx) * 32;

    __shared__ float tile[32][33];
    const int tx = threadIdx.x & 31, ty = threadIdx.x >> 5;  // 32 x 8
    #pragma unroll
    for (int i = 0; i < 4; ++i)
        tile[ty + 8*i][tx] = ldS(d.in, (size_t)(r0 + ty + 8*i) * d.Cc + c0 + tx, f);
    __syncthreads();
    #pragma unroll
    for (int i = 0; i < 4; ++i)
        d.out[(size_t)(c0 + ty + 8*i) * d.R + r0 + tx] = f2b(tile[tx][ty + 8*i]);
}

// ---------------------------------------------------------------------------
// Transpose V half of kv [4096][4096] into vT[(b*H+h)*HD + d][t].
// ---------------------------------------------------------------------------
__global__ __launch_bounds__(256) void transpose_v_kernel(const bf16* __restrict__ kvb,
                                                          bf16* __restrict__ vT)
{
    __shared__ bf16 tile[32][34];
    const int c0 = blockIdx.x * 32;        // v-col 0..2047
    const int r0 = blockIdx.y * 32;        // row 0..4095 (b*T + t)
    const int tx = threadIdx.x & 31, ty = threadIdx.x >> 5;
    #pragma unroll
    for (int i = 0; i < 4; ++i)
        tile[ty + 8*i][tx] = kvb[(size_t)(r0 + ty + 8*i) * (H_*256) + H_*128 + c0 + tx];
    __syncthreads();
    const int b  = r0 >> 11;
    const int t0 = r0 & (T_ - 1);
    #pragma unroll
    for (int i = 0; i < 4; ++i) {
        const int c  = c0 + ty + 8*i;
        const int hh = c >> 7, dd = c & 127;
        vT[(((size_t)b*H_ + hh)*HD_ + dd)*T_ + t0 + tx] = tile[tx][ty + 8*i];
    }
}

struct GOuts { void* p[3]; int start[3]; int stride[3]; int nseg; };

// ---------------------------------------------------------------------------
// mfma_gemm (legacy 128x128, 2-phase): kept ONLY for the 64-wide k_pe tail.
// ---------------------------------------------------------------------------
__global__ __launch_bounds__(256) void mfma_gemm(const bf16* __restrict__ A,
                                                 const bf16* __restrict__ BT,
                                                 GOuts go, int N, int K,
                                                 const int* __restrict__ flag, int cH,
                                                 int bnOff)
{
    const int cf = cH ? *flag : 0;
    __shared__ bf16 As[128 * 32];
    __shared__ bf16 Bs[128 * 32];
    const int tid  = threadIdx.x;
    const int w    = tid >> 6;
    const int lane = tid & 63;
    const int quad = lane >> 4;
    const int l16  = lane & 15;
    const int wm   = w >> 1, wn = w & 1;
    const int bm   = blockIdx.y * 128, bn = (blockIdx.x + bnOff) * 128;
    const int lrow = lane >> 2;
    const int lk   = (lane & 3) * 8;

    int seg = 0;
    #pragma unroll
    for (int i = 1; i < 3; ++i)
        if (i < go.nseg && bn >= go.start[i]) seg = i;
    void* const dstp   = go.p[seg];
    const int  dstoff  = go.start[seg];
    const int  dstride = go.stride[seg];

    f32x4 acc[4][4];
    #pragma unroll
    for (int i = 0; i < 4; ++i)
        #pragma unroll
        for (int j = 0; j < 4; ++j)
            acc[i][j] = (f32x4){0.f, 0.f, 0.f, 0.f};

    for (int kk = 0; kk < K; kk += 32) {
        if (kk) __syncthreads();
        #pragma unroll
        for (int c = 0; c < 2; ++c) {
            const int ch  = w * 2 + c;
            const int row = ch * 16 + lrow;
            const bf16* g = A + (size_t)(bm + row) * K + kk + lk;
            __builtin_amdgcn_global_load_lds(
                (const __attribute__((address_space(1))) unsigned int*)g,
                (__attribute__((address_space(3))) unsigned int*)(As + ch * 512),
                16, 0, 0);
        }
        #pragma unroll
        for (int c = 0; c < 2; ++c) {
            const int ch  = w * 2 + c;
            const int row = ch * 16 + lrow;
            const bf16* g = BT + (size_t)(bn + row) * K + kk + lk;
            __builtin_amdgcn_global_load_lds(
                (const __attribute__((address_space(1))) unsigned int*)g,
                (__attribute__((address_space(3))) unsigned int*)(Bs + ch * 512),
                16, 0, 0);
        }
        __syncthreads();

        s16x8 af[4], bfv[4];
        #pragma unroll
        for (int i = 0; i < 4; ++i)
            af[i] = *(const s16x8*)&As[(wm*64 + i*16 + l16) * 32 + quad*8];
        #pragma unroll
        for (int j = 0; j < 4; ++j)
            bfv[j] = *(const s16x8*)&Bs[(wn*64 + j*16 + l16) * 32 + quad*8];
        #pragma unroll
        for (int i = 0; i < 4; ++i)
            #pragma unroll
            for (int j = 0; j < 4; ++j)
                acc[i][j] = __builtin_amdgcn_mfma_f32_16x16x32_bf16(af[i], bfv[j], acc[i][j], 0, 0, 0);
    }

    #pragma unroll
    for (int i = 0; i < 4; ++i) {
        const int crow = bm + wm*64 + i*16 + quad*4;
        #pragma unroll
        for (int r = 0; r < 4; ++r) {
            #pragma unroll
            for (int j = 0; j < 4; ++j) {
                const int ccol = bn + wn*64 + j*16 + l16;
                if (ccol < N) {
                    const size_t idx = (size_t)(crow + r) * dstride + (ccol - dstoff);
                    if (cf) ((float*)dstp)[idx] = acc[i][j][r];
                    else    ((bf16*)dstp)[idx] = f2b(acc[i][j][r]);
                }
            }
        }
    }
}

// ---------------------------------------------------------------------------
// gemm256: 256x256 8-phase deep-pipelined GEMM.
// ROUND-4 FIX: full (row&7) XOR slot-swizzle. Round-3's key had only 2
// values -> 16 lanes on 2 slots = 8-way bank conflict on every ds_read_b128
// (the T2-gate mechanism made this the critical path; ~350 TF observed).
// Correct form (G4): rows stride 128B == 0 mod 32 dwords, so:
//   write: dest linear (row=tid>>3, slot=tid&7); global source 16B-col
//          = (tid&7) ^ ((tid>>3)&7)   [same involution, rule 21]
//   read:  physical slot = (ks*4+quad) ^ (l16&7)
// -> quad phase-group: 8 slots x 2 lanes, rows 8 apart (same banks) = 2-way
//    = free (m136).
// ---------------------------------------------------------------------------
__global__ __launch_bounds__(512, 2) void gemm256(const bf16* __restrict__ A,
                                                  const bf16* __restrict__ BT,
                                                  GOuts go, int N, int K,
                                                  const int* __restrict__ flag, int cH)
{
    extern __shared__ __align__(16) char smem[];
    const int cf   = cH ? *flag : 0;
    const int tid  = threadIdx.x;
    const int lane = tid & 63;
    const int quad = lane >> 4;
    const int l16  = lane & 15;
    const int wid  = tid >> 6;
    const int wm   = wid >> 2, wn = wid & 3;
    const int bm   = blockIdx.y * 256, bn = blockIdx.x * 256;

    int seg = 0;
    #pragma unroll
    for (int i = 1; i < 3; ++i)
        if (i < go.nseg && bn >= go.start[i]) seg = i;
    void* const dstp   = go.p[seg];
    const int  dstoff  = go.start[seg];
    const int  dstride = go.stride[seg];

    const int nkt = K >> 6;      // K-tiles of 64
    const int nit = nkt >> 1;    // 2 tiles per iteration

    // staging: inverse-swizzled global source, linear LDS dest
    const int sR   = tid >> 3;                          // row within 64-row group
    const int sCol = ((tid & 7) ^ (sR & 7)) * 8;        // bf16 col: slot ^ (row&7)
    // ds_read swizzle key: full row&7
    const int rxk  = l16 & 7;
    const int aBase = wm*16384 + l16*128;
    const int bBase = 32768 + (wn>>1)*16384 + ((wn&1)*64 + l16)*128;

    f32x4 acc[8][4];
    #pragma unroll
    for (int i = 0; i < 8; ++i)
        #pragma unroll
        for (int j = 0; j < 4; ++j)
            acc[i][j] = (f32x4){0.f,0.f,0.f,0.f};

    s16x8 ar[4][2];       // current A quadrant frags [m][ks]
    s16x8 br[2][2][2];    // B frags [qn][n][ks]

    #define STG(op, buf, half, kt) do {                                          \
        const int ktc_ = ((kt) < nkt ? (kt) : nkt-1);                            \
        const bf16* base_ = (op) ? BT : A;                                       \
        const int rb_ = ((op) ? bn : bm) + (half)*128;                           \
        char* ld_ = smem + (buf)*65536 + (op)*32768 + (half)*16384;              \
        _Pragma("unroll")                                                        \
        for (int j_ = 0; j_ < 2; ++j_) {                                         \
            const bf16* g_ = base_ + (size_t)(rb_ + j_*64 + sR) * K              \
                             + ktc_*64 + sCol;                                   \
            __builtin_amdgcn_global_load_lds(                                    \
                (const __attribute__((address_space(1))) unsigned int*)g_,       \
                (__attribute__((address_space(3))) unsigned int*)(ld_ + j_*8192 + tid*16), \
                16, 0, 0);                                                       \
        }                                                                        \
    } while (0)

    #define LDA(buf, qm) do {                                                    \
        _Pragma("unroll")                                                        \
        for (int mm_ = 0; mm_ < 4; ++mm_)                                        \
            _Pragma("unroll")                                                    \
            for (int ks_ = 0; ks_ < 2; ++ks_)                                    \
                ar[mm_][ks_] = *(const s16x8*)(smem + (buf)*65536 + aBase        \
                                 + ((qm)*4+mm_)*2048                             \
                                 + ((((ks_<<2)|quad) ^ rxk) << 4));              \
    } while (0)

    #define LDB(buf, qn) do {                                                    \
        _Pragma("unroll")                                                        \
        for (int nn_ = 0; nn_ < 2; ++nn_)                                        \
            _Pragma("unroll")                                                    \
            for (int ks_ = 0; ks_ < 2; ++ks_)                                    \
                br[qn][nn_][ks_] = *(const s16x8*)(smem + (buf)*65536 + bBase    \
                                 + ((qn)*2+nn_)*2048                             \
                                 + ((((ks_<<2)|quad) ^ rxk) << 4));              \
    } while (0)

    #define MM(qm, qn) do {                                                      \
        __builtin_amdgcn_s_setprio(1);                                           \
        _Pragma("unroll")                                                        \
        for (int mm_ = 0; mm_ < 4; ++mm_)                                        \
            _Pragma("unroll")                                                    \
            for (int nn_ = 0; nn_ < 2; ++nn_)                                    \
                _Pragma("unroll")                                                \
                for (int ks_ = 0; ks_ < 2; ++ks_)                                \
                    acc[(qm)*4+mm_][(qn)*2+nn_] =                                \
                        __builtin_amdgcn_mfma_f32_16x16x32_bf16(                 \
                            ar[mm_][ks_], br[qn][nn_][ks_],                      \
                            acc[(qm)*4+mm_][(qn)*2+nn_], 0, 0, 0);               \
        __builtin_amdgcn_s_setprio(0);                                           \
    } while (0)

    #define BARR __builtin_amdgcn_s_barrier()
    #define VMC(n) asm volatile("s_waitcnt vmcnt(" #n ")" ::: "memory")

    // prologue: tile0 fully into buf0, tile1.Ah0 into buf1
    STG(0,0,0, 0); STG(0,0,1, 0); STG(1,0,0, 0); STG(1,0,1, 0);
    STG(0,1,0, 1);
    VMC(0); BARR;

    for (int i = 0; i < nit; ++i) {
        const int tB = 2*i + 1;   // buf1's tile (finishing its staging)
        const int tA = 2*i + 2;   // buf0's next tile
        const int tC = 2*i + 3;   // buf1's next tile (first half-tile)

        // ph1
        LDA(0,0); LDB(0,0); STG(0,1,1, tB); BARR; MM(0,0); BARR;
        // ph2
        LDB(0,1);           STG(1,1,0, tB); BARR; MM(0,1); BARR;
        // ph3
        LDA(0,1);           STG(1,1,1, tB); BARR; MM(1,1); BARR;
        // ph4
        STG(0,0,0, tA); VMC(2); BARR; MM(1,0); BARR;
        // ph5
        LDA(1,0); LDB(1,0); STG(0,0,1, tA); BARR; MM(0,0); BARR;
        // ph6
        LDB(1,1);           STG(1,0,0, tA); BARR; MM(0,1); BARR;
        // ph7
        LDA(1,1);           STG(1,0,1, tA); BARR; MM(1,1); BARR;
        // ph8
        STG(0,1,0, tC); VMC(2); BARR; MM(1,0); BARR;
    }

    VMC(0);

    #undef STG
    #undef LDA
    #undef LDB
    #undef MM
    #undef BARR
    #undef VMC

    #pragma unroll
    for (int mm = 0; mm < 8; ++mm) {
        const int crow = bm + wm*128 + mm*16 + quad*4;
        #pragma unroll
        for (int r = 0; r < 4; ++r) {
            #pragma unroll
            for (int nn = 0; nn < 4; ++nn) {
                const int ccol = bn + wn*64 + nn*16 + l16;
                const size_t idx = (size_t)(crow + r) * dstride + (ccol - dstoff);
                if (cf) ((float*)dstp)[idx] = acc[mm][nn][r];
                else    ((bf16*)dstp)[idx] = f2b(acc[mm][nn][r]);
            }
        }
    }
}

// ---------------------------------------------------------------------------
// In-place RMSNorm over rows of X [rows, NPER*256] (internal bf16)
// ---------------------------------------------------------------------------
template<int NPER>
__global__ __launch_bounds__(256) void rms_kernel(bf16* __restrict__ X,
                                                  const void* __restrict__ w,
                                                  const int* __restrict__ flag)
{
    const int wf = *flag;
    const int ncols = NPER * 256;
    __shared__ float red[4];
    const int row = blockIdx.x;
    const int tid = threadIdx.x;
    bf16* xr = X + (size_t)row * ncols;
    float vals[NPER];
    float ss = 0.f;
    #pragma unroll
    for (int i = 0; i < NPER; ++i) {
        float v = b2f(xr[tid + i*256]);
        vals[i] = v; ss += v*v;
    }
    #pragma unroll
    for (int off = 32; off; off >>= 1) ss += __shfl_down(ss, off, 64);
    if ((tid & 63) == 0) red[tid >> 6] = ss;
    __syncthreads();
    const float tot = red[0]+red[1]+red[2]+red[3];
    const float rs  = rsqrtf(tot / (float)ncols + 1e-6f);
    #pragma unroll
    for (int i = 0; i < NPER; ++i) {
        const int c = tid + i*256;
        xr[c] = f2b(vals[i] * rs * ldS(w, c, wf));
    }
}

// ---------------------------------------------------------------------------
// k_pe: in-place RMSNorm over 64 cols + RoPE
// ---------------------------------------------------------------------------
__global__ __launch_bounds__(64) void kpe_rms_rope(bf16* __restrict__ X,
                                                   const void* __restrict__ w,
                                                   const int* __restrict__ flag)
{
    const int wf   = *flag;
    const int row  = blockIdx.x;
    const int t    = row & (T_ - 1);
    const int lane = threadIdx.x;
    bf16* xr = X + (size_t)row * RD_;
    const float v = b2f(xr[lane]);
    float ss = v * v;
    #pragma unroll
    for (int off = 32; off; off >>= 1) ss += __shfl_down(ss, off, 64);
    ss = __shfl(ss, 0, 64);
    const float rs = rsqrtf(ss / 64.f + 1e-6f);
    const float xn = v * rs * ldS(w, lane, wf);
    const int   i  = lane & 31;
    const float freq = powf(10000.f, -(float)(2*i) / 64.f);
    const float ang  = (float)t * freq;
    const float s = sinf(ang), c = cosf(ang);
    const float other = __shfl_xor(xn, 32, 64);
    const float o = (lane < 32) ? (xn * c - other * s) : (other * s + xn * c);
    xr[lane] = f2b(o);
}

// ---------------------------------------------------------------------------
// q_pe RoPE in-place: X [B*T, H*64]
// ---------------------------------------------------------------------------
__global__ __launch_bounds__(256) void qpe_rope(bf16* __restrict__ X)
{
    const int row = blockIdx.x;
    const int t   = row & (T_ - 1);
    bf16* xr = X + (size_t)row * (H_ * RD_);
    const int tid = threadIdx.x;
    #pragma unroll
    for (int pp = 0; pp < 2; ++pp) {
        const int p  = tid + pp * 256;
        const int hh = p >> 5;
        const int i  = p & 31;
        const int i0 = hh * 64 + i;
        const int i1 = i0 + 32;
        const float x1 = b2f(xr[i0]), x2 = b2f(xr[i1]);
        const float freq = powf(10000.f, -(float)(2*i) / 64.f);
        const float ang  = (float)t * freq;
        const float s = sinf(ang), c = cosf(ang);
        xr[i0] = f2b(x1 * c - x2 * s);
        xr[i1] = f2b(x1 * s + x2 * c);
    }
}

// ---------------------------------------------------------------------------
// Flash-style MFMA attention v5 (passing @114.5us, round-2 verified):
// tight LDS + XOR swizzle (48KB, 3 blocks/CU), spill-free softmax.
// ---------------------------------------------------------------------------
__global__ __launch_bounds__(256, 2) void flash_attn(const bf16* __restrict__ qnop,
                                                     const bf16* __restrict__ qpe,
                                                     const bf16* __restrict__ kv,
                                                     const bf16* __restrict__ kpe,
                                                     const bf16* __restrict__ vT,
                                                     bf16* __restrict__ y)
{
    __shared__ __align__(16) short Klds[64 * 192];
    __shared__ __align__(16) short Vt[128 * 64];
    __shared__ __align__(16) short Plds[4][16 * 64];

    const int h   = blockIdx.x;
    const int qt  = 31 - (int)blockIdx.y;          // heavy blocks dispatched first
    const int b   = blockIdx.z;
    const int q0  = qt * 64;
    const int tid = threadIdx.x;
    const int w    = tid >> 6;
    const int lane = tid & 63;
    const int quad = lane >> 4;
    const int l16  = lane & 15;
    const int rk   = l16 & 7;
    const int rkp  = (l16 ^ (l16 >> 3)) & 7;
    const int row0 = q0 + w * 16;
    const size_t bT = (size_t)b * T_;
    const int bh  = b * H_ + h;

    const int kR = tid >> 4, kS = tid & 15;
    const int pR = tid >> 3, pS = tid & 7;
    const int vD = tid >> 3, vS = tid & 7;

    const bf16* gK = kv  + (bT + kR) * (H_*256) + h*128 + kS*8;
    const bf16* gP = kpe + (bT + pR) * RD_ + pS*8;
    const bf16* gV = vT  + ((size_t)bh*HD_ + vD) * T_ + vS*8;

    short* const wK = &Klds[kR*192 + ((kS ^ (kR & 7)) << 3)];
    short* const wP = &Klds[pR*192 + 128 + ((pS ^ (pR & 7)) << 3)];
    short* const wV = &Vt[vD*64 + ((vS ^ (vD & 7)) << 3)];

    s16x8 aq[6];
    {
        const size_t r = bT + row0 + l16;
        const bf16* qn = qnop + r * (H_*128) + h*128 + quad*8;
        #pragma unroll
        for (int kk = 0; kk < 4; ++kk) aq[kk] = *(const s16x8*)(qn + kk*32);
        const bf16* qp = qpe + r * (H_*64) + h*64 + quad*8;
        aq[4] = *(const s16x8*)(qp);
        aq[5] = *(const s16x8*)(qp + 32);
    }

    f32x4 o[8];
    #pragma unroll
    for (int i = 0; i < 8; ++i) o[i] = (f32x4){0.f,0.f,0.f,0.f};
    float m_run[4] = {-1e30f,-1e30f,-1e30f,-1e30f};
    float l_run[4] = {0.f,0.f,0.f,0.f};

    uint4 k0, k1, k2, k3, p0, p1, v0, v1, v2, v3;
    #define PF(J0) do {                                                     \
        const bf16* a_ = gK + (size_t)(J0) * (H_*256);                      \
        k0 = *(const uint4*)(a_);                                           \
        k1 = *(const uint4*)(a_ + 16*(H_*256));                             \
        k2 = *(const uint4*)(a_ + 32*(H_*256));                             \
        k3 = *(const uint4*)(a_ + 48*(H_*256));                             \
        const bf16* p_ = gP + (size_t)(J0) * RD_;                           \
        p0 = *(const uint4*)(p_);                                           \
        p1 = *(const uint4*)(p_ + 32*RD_);                                  \
        const bf16* v_ = gV + (J0);                                         \
        v0 = *(const uint4*)(v_);                                           \
        v1 = *(const uint4*)(v_ + 32*T_);                                   \
        v2 = *(const uint4*)(v_ + 64*T_);                                   \
        v3 = *(const uint4*)(v_ + 96*T_);                                   \
    } while (0)

    PF(0);

    const int ntiles = qt + 1;
    for (int it = 0; it < ntiles; ++it) {
        const int j0 = it * 64;
        asm volatile("s_waitcnt lgkmcnt(0)\n\ts_barrier" ::: "memory");

        *(uint4*)(wK)          = k0;
        *(uint4*)(wK + 16*192) = k1;
        *(uint4*)(wK + 32*192) = k2;
        *(uint4*)(wK + 48*192) = k3;
        *(uint4*)(wP)          = p0;
        *(uint4*)(wP + 32*192) = p1;
        *(uint4*)(wV)          = v0;
        *(uint4*)(wV + 32*64)  = v1;
        *(uint4*)(wV + 64*64)  = v2;
        *(uint4*)(wV + 96*64)  = v3;

        if (it + 1 < ntiles) PF(j0 + 64);

        asm volatile("s_waitcnt lgkmcnt(0)\n\ts_barrier" ::: "memory");

        if (j0 <= row0 + 15) {
            const bool needmask = (j0 + 63 > row0);
            f32x4 s[4];
            #pragma unroll
            for (int nsub = 0; nsub < 4; ++nsub) {
                f32x4 acc = (f32x4){0.f,0.f,0.f,0.f};
                #pragma unroll
                for (int kk = 0; kk < 6; ++kk) {
                    const s16x8 bk = *(const s16x8*)&Klds[(nsub*16 + l16)*192
                                        + ((((kk << 2) | quad) ^ rk) << 3)];
                    acc = __builtin_amdgcn_mfma_f32_16x16x32_bf16(aq[kk], bk, acc, 0, 0, 0);
                }
                #pragma unroll
                for (int reg = 0; reg < 4; ++reg) acc[reg] *= SCALE_;
                s[nsub] = acc;
            }
            if (needmask) {
                #pragma unroll
                for (int nsub = 0; nsub < 4; ++nsub)
                    #pragma unroll
                    for (int reg = 0; reg < 4; ++reg) {
                        const int col = j0 + nsub*16 + l16;
                        const int row = row0 + quad*4 + reg;
                        if (col > row) s[nsub][reg] = -1e30f;
                    }
            }
            float mt[4], alpha[4], rs[4];
            #pragma unroll
            for (int reg = 0; reg < 4; ++reg)
                mt[reg] = fmaxf(fmaxf(s[0][reg], s[1][reg]), fmaxf(s[2][reg], s[3][reg]));
            #pragma unroll
            for (int d = 1; d < 16; d <<= 1)
                #pragma unroll
                for (int reg = 0; reg < 4; ++reg)
                    mt[reg] = fmaxf(mt[reg], __shfl_xor(mt[reg], d, 64));
            #pragma unroll
            for (int reg = 0; reg < 4; ++reg) {
                const float mnew = fmaxf(m_run[reg], mt[reg]);
                alpha[reg] = __expf(m_run[reg] - mnew);
                m_run[reg] = mnew;
                rs[reg] = 0.f;
            }
            #pragma unroll
            for (int nsub = 0; nsub < 4; ++nsub)
                #pragma unroll
                for (int reg = 0; reg < 4; ++reg) {
                    const float p = __expf(s[nsub][reg] - m_run[reg]);
                    s[nsub][reg] = p;
                    rs[reg] += p;
                }
            #pragma unroll
            for (int d = 1; d < 16; d <<= 1)
                #pragma unroll
                for (int reg = 0; reg < 4; ++reg)
                    rs[reg] += __shfl_xor(rs[reg], d, 64);
            #pragma unroll
            for (int reg = 0; reg < 4; ++reg)
                l_run[reg] = l_run[reg] * alpha[reg] + rs[reg];

            #pragma unroll
            for (int nsub = 0; nsub < 4; ++nsub)
                #pragma unroll
                for (int reg = 0; reg < 4; ++reg) {
                    const bf16 pv = f2b(s[nsub][reg]);
                    const int prow = (quad << 2) + reg;
                    const int pk   = (prow ^ (prow >> 3)) & 7;
                    const int pby  = ((nsub << 5) + (l16 << 1)) ^ (pk << 4);
                    Plds[w][prow*64 + (pby >> 1)] = *(const short*)&pv;
                }
            #pragma unroll
            for (int n2 = 0; n2 < 8; ++n2)
                #pragma unroll
                for (int reg = 0; reg < 4; ++reg)
                    o[n2][reg] *= alpha[reg];

            const s16x8 ap0 = *(const s16x8*)&Plds[w][l16*64 + (((quad    ) ^ rkp) << 3)];
            const s16x8 ap1 = *(const s16x8*)&Plds[w][l16*64 + (((quad | 4) ^ rkp) << 3)];
            #pragma unroll
            for (int n2 = 0; n2 < 8; ++n2) {
                const s16x8 bv0 = *(const s16x8*)&Vt[(n2*16 + l16)*64 + (((quad    ) ^ rk) << 3)];
                const s16x8 bv1 = *(const s16x8*)&Vt[(n2*16 + l16)*64 + (((quad | 4) ^ rk) << 3)];
                o[n2] = __builtin_amdgcn_mfma_f32_16x16x32_bf16(ap0, bv0, o[n2], 0, 0, 0);
                o[n2] = __builtin_amdgcn_mfma_f32_16x16x32_bf16(ap1, bv1, o[n2], 0, 0, 0);
            }
        }
    }
    #undef PF

    #pragma unroll
    for (int reg = 0; reg < 4; ++reg) {
        const float inv = 1.f / l_run[reg];
        const size_t r = bT + row0 + quad*4 + reg;
        bf16* yr = y + r * (H_*128) + h*128 + l16;
        #pragma unroll
        for (int n2 = 0; n2 < 8; ++n2)
            yr[n2*16] = f2b(o[n2][reg] * inv);
    }
}

// ---------------------------------------------------------------------------
extern "C" void kernel_launch(void* const* d_in, const int* in_sizes, int n_in,
                              void* d_out, int out_size, void* d_ws, size_t ws_size,
                              hipStream_t stream)
{
    const void* x         = d_in[0];
    const void* Wq_down   = d_in[1];
    const void* q_norm_w  = d_in[2];
    const void* Wq_up     = d_in[3];
    const void* Wq_pe     = d_in[4];
    const void* Wkv_down  = d_in[5];
    const void* kv_norm_w = d_in[6];
    const void* Wkv_up    = d_in[7];
    const void* Wk_pe     = d_in[8];
    const void* kpe_nw    = d_in[9];
    const void* Wo        = d_in[10];

    char* ws = (char*)d_ws;
    int*  flag = (int*)(ws + 0);
    bf16* xb   = (bf16*)(ws + 256);        // [4096,2048] — dead after x-GEMM; reused as vT
    bf16* cQ   = (bf16*)(ws + 16777472);   // [4096,1536] — dead after q-GEMM; reused as P3/P4
    bf16* cKV  = (bf16*)(ws + 29360384);   // [4096, 512]
    bf16* kpeb = (bf16*)(ws + 33554688);   // [4096,  64]
    bf16* qnop = (bf16*)(ws + 34078976);   // [4096,2048]
    bf16* qpeb = (bf16*)(ws + 50856192);   // [4096,1024]
    bf16* kvb  = (bf16*)(ws + 59244800);   // [4096,4096] — written late; holds P1/P2 early
    bf16* yb   = (bf16*)(ws + 92799232);   // [4096,2048]  (end 109,576,448)

    // weight arenas (lifetime-safe overlays):
    bf16* P1 = kvb;                            // [2176][2048] x-weights^T (8.9 MB)
    bf16* P2 = (bf16*)((char*)kvb + 8912896);  // [3072][1536] q-weights^T (9.4 MB)
    bf16* P3 = cQ;                             // [4096][512]  Wkv_up^T    (4.2 MB)
    bf16* P4 = (bf16*)((char*)cQ + 4194304);   // [2048][2048] Wo^T        (8.4 MB)
    bf16* vT = xb;                             // [B*H][128][2048] V^T

    const dim3 blk(256);
    const dim3 blk512(512);

    static int attr_set = 0;
    if (!attr_set) {
        hipFuncSetAttribute(reinterpret_cast<const void*>(gemm256),
                            hipFuncAttributeMaxDynamicSharedMemorySize, 131072);
        attr_set = 1;
    }

    detect_kernel<<<1, dim3(64), 0, stream>>>((const unsigned short*)x, flag);
    convert_kernel<<<(B_*T_*C_)/(256*8), blk, 0, stream>>>(x, xb, B_*T_*C_, flag);

    // ---- batched transpose #1: x-path + q-path weights ----
    {
        TBatch tb;
        tb.d[0] = { Wq_down,  P1,               C_,  QLR_,     0, QLR_/32 };    // 3072 blks
        tb.d[1] = { Wkv_down, P1 + 1536*2048,   C_,  KLR_,  3072, KLR_/32 };    // 1024
        tb.d[2] = { Wk_pe,    P1 + 2048*2048,   C_,  RD_,   4096, RD_/32  };    //  128
        tb.d[3] = { Wq_up,    P2,               QLR_, 2048, 4224, 2048/32 };    // 3072
        tb.d[4] = { Wq_pe,    P2 + 2048*1536,   QLR_, 1024, 7296, 1024/32 };    // 1536
        tb.nseg = 5;
        transpose_batch<<<8832, blk, 0, stream>>>(tb, flag);
    }

    // ---- x-projection: cQ|cKV via gemm256 (N=2048), k_pe tail via legacy ----
    {
        GOuts go; go.nseg = 2;
        go.p[0]=cQ;   go.start[0]=0;    go.stride[0]=QLR_;
        go.p[1]=cKV;  go.start[1]=1536; go.stride[1]=KLR_;
        go.p[2]=nullptr; go.start[2]=0; go.stride[2]=0;
        gemm256<<<dim3(8, 16), blk512, 131072, stream>>>(xb, P1, go, 2048, C_, flag, 0);
    }
    {
        GOuts go; go.nseg = 1;
        go.p[0]=kpeb; go.start[0]=2048; go.stride[0]=RD_;
        go.p[1]=nullptr; go.start[1]=0; go.stride[1]=0;
        go.p[2]=nullptr; go.start[2]=0; go.stride[2]=0;
        mfma_gemm<<<dim3(1, 32), blk, 0, stream>>>(xb, P1, go, 2112, C_, flag, 0, 16);
    }
    rms_kernel<6><<<B_*T_, blk, 0, stream>>>(cQ, q_norm_w, flag);
    rms_kernel<2><<<B_*T_, blk, 0, stream>>>(cKV, kv_norm_w, flag);
    kpe_rms_rope<<<B_*T_, dim3(64), 0, stream>>>(kpeb, kpe_nw, flag);

    // ---- fused q-projection GEMM: cQ @ [Wq_up | Wq_pe] ----
    {
        GOuts go; go.nseg = 2;
        go.p[0]=qnop; go.start[0]=0;    go.stride[0]=H_*HD_;
        go.p[1]=qpeb; go.start[1]=2048; go.stride[1]=H_*RD_;
        go.p[2]=nullptr; go.start[2]=0; go.stride[2]=0;
        gemm256<<<dim3(12, 16), blk512, 131072, stream>>>(cQ, P2, go, 3072, QLR_, flag, 0);
    }
    qpe_rope<<<B_*T_, blk, 0, stream>>>(qpeb);

    // ---- batched transpose #2: Wkv_up, Wo (cQ now dead) ----
    {
        TBatch tb;
        tb.d[0] = { Wkv_up, P3, KLR_, H_*2*HD_,    0, (H_*2*HD_)/32 };  // 2048 blks
        tb.d[1] = { Wo,     P4, H_*HD_, C_,     2048, C_/32 };          // 4096
        tb.d[2] = tb.d[1]; tb.d[3] = tb.d[1]; tb.d[4] = tb.d[1];
        tb.nseg = 2;
        transpose_batch<<<6144, blk, 0, stream>>>(tb, flag);
    }

    // ---- kv up-projection, then V transpose (xb dead) ----
    {
        GOuts go; go.nseg = 1;
        go.p[0]=kvb; go.start[0]=0; go.stride[0]=H_*2*HD_;
        go.p[1]=nullptr; go.start[1]=0; go.stride[1]=0;
        go.p[2]=nullptr; go.start[2]=0; go.stride[2]=0;
        gemm256<<<dim3(16, 16), blk512, 131072, stream>>>(cKV, P3, go, H_*2*HD_, KLR_, flag, 0);
    }
    transpose_v_kernel<<<dim3((H_*HD_)/32, (B_*T_)/32), blk, 0, stream>>>(kvb, vT);

    // ---- attention ----
    flash_attn<<<dim3(H_, T_/64, B_), blk, 0, stream>>>(qnop, qpeb, kvb, kpeb, vT, yb);

    // ---- output projection (dtype of d_out per flag) ----
    {
        GOuts go; go.nseg = 1;
        go.p[0]=d_out; go.start[0]=0; go.stride[0]=C_;
        go.p[1]=nullptr; go.start[1]=0; go.stride[1]=0;
        go.p[2]=nullptr; go.start[2]=0; go.stride[2]=0;
        gemm256<<<dim3(8, 16), blk512, 131072, stream>>>(yb, P4, go, C_, H_*HD_, flag, 1);
    }
}

// Round 5
// 455.672 us; speedup vs baseline: 1.1843x; 1.1422x over previous
//
#include <hip/hip_runtime.h>
#include <hip/hip_bf16.h>
#include <cmath>

typedef __hip_bfloat16 bf16;
typedef __attribute__((ext_vector_type(8))) short s16x8;
typedef __attribute__((ext_vector_type(4))) float f32x4;

#define B_   2
#define T_   2048
#define C_   2048
#define H_   16
#define HD_  128
#define RD_  64
#define QLR_ 1536
#define KLR_ 512
#define SCALE_ 0.07216878364870322f   // (128+64)^-0.5

static __device__ __forceinline__ float b2f(bf16 v){ return __bfloat162float(v); }
static __device__ __forceinline__ bf16  f2b(float v){ return __float2bfloat16(v); }
static __device__ __forceinline__ float us2f(unsigned short u){
    union { unsigned short s[2]; float f; } v; v.s[0]=0; v.s[1]=u; return v.f;
}
static __device__ __forceinline__ float ldS(const void* p, size_t i, int isf32){
    return isf32 ? ((const float*)p)[i] : b2f(((const bf16*)p)[i]);
}
static __device__ __forceinline__ void ld4(const void* p, size_t i, int isf32, float* o){
    if (isf32) {
        float4 v = *(const float4*)((const float*)p + i);
        o[0]=v.x; o[1]=v.y; o[2]=v.z; o[3]=v.w;
    } else {
        ushort4 u = *(const ushort4*)((const bf16*)p + i);
        o[0]=us2f(u.x); o[1]=us2f(u.y); o[2]=us2f(u.z); o[3]=us2f(u.w);
    }
}

// ---------------------------------------------------------------------------
// dtype detector (1 = harness buffers are f32, 0 = bf16)
// ---------------------------------------------------------------------------
__global__ __launch_bounds__(64) void detect_kernel(const unsigned short* __restrict__ x,
                                                    int* __restrict__ flag)
{
    int big = 0;
    for (int i = threadIdx.x; i < 1024; i += 64) {
        const unsigned short u = x[2*i];
        const int e = (u >> 7) & 0xFF;
        if (e >= 139) big++;
    }
    #pragma unroll
    for (int off = 32; off; off >>= 1) big += __shfl_down(big, off, 64);
    if (threadIdx.x == 0) *flag = (big > 8) ? 1 : 0;
}

// ---------------------------------------------------------------------------
// Elementwise convert harness buffer -> bf16 (8 elems/thread)
// ---------------------------------------------------------------------------
__global__ __launch_bounds__(256) void convert_kernel(const void* __restrict__ in,
                                                      bf16* __restrict__ out, int n,
                                                      const int* __restrict__ flag)
{
    const int f = *flag;
    const int i0 = (blockIdx.x * 256 + threadIdx.x) * 8;
    if (i0 >= n) return;
    float v[8];
    ld4(in, i0, f, v);
    ld4(in, i0 + 4, f, v + 4);
    bf16* o = out + i0;
    #pragma unroll
    for (int k = 0; k < 8; ++k) o[k] = f2b(v[k]);
}

// ---------------------------------------------------------------------------
// Batched transpose: several harness weights [R][Cc] -> bf16 [Cc][R].
// ---------------------------------------------------------------------------
struct TDesc { const void* in; bf16* out; int R, Cc, blkStart, nx; };
struct TBatch { TDesc d[5]; int nseg; };

__global__ __launch_bounds__(256) void transpose_batch(TBatch tb,
                                                       const int* __restrict__ flag)
{
    const int f = *flag;
    const int bid = blockIdx.x;
    int s = 0;
    #pragma unroll
    for (int i = 1; i < 5; ++i)
        if (i < tb.nseg && bid >= tb.d[i].blkStart) s = i;
    const TDesc d = tb.d[s];
    const int local = bid - d.blkStart;
    const int c0 = (local % d.nx) * 32;
    const int r0 = (local / d.nx) * 32;

    __shared__ float tile[32][33];
    const int tx = threadIdx.x & 31, ty = threadIdx.x >> 5;  // 32 x 8
    #pragma unroll
    for (int i = 0; i < 4; ++i)
        tile[ty + 8*i][tx] = ldS(d.in, (size_t)(r0 + ty + 8*i) * d.Cc + c0 + tx, f);
    __syncthreads();
    #pragma unroll
    for (int i = 0; i < 4; ++i)
        d.out[(size_t)(c0 + ty + 8*i) * d.R + r0 + tx] = f2b(tile[tx][ty + 8*i]);
}

// ---------------------------------------------------------------------------
// Transpose V half of kv [4096][4096] into vT[(b*H+h)*HD + d][t].
// ---------------------------------------------------------------------------
__global__ __launch_bounds__(256) void transpose_v_kernel(const bf16* __restrict__ kvb,
                                                          bf16* __restrict__ vT)
{
    __shared__ bf16 tile[32][34];
    const int c0 = blockIdx.x * 32;        // v-col 0..2047
    const int r0 = blockIdx.y * 32;        // row 0..4095 (b*T + t)
    const int tx = threadIdx.x & 31, ty = threadIdx.x >> 5;
    #pragma unroll
    for (int i = 0; i < 4; ++i)
        tile[ty + 8*i][tx] = kvb[(size_t)(r0 + ty + 8*i) * (H_*256) + H_*128 + c0 + tx];
    __syncthreads();
    const int b  = r0 >> 11;
    const int t0 = r0 & (T_ - 1);
    #pragma unroll
    for (int i = 0; i < 4; ++i) {
        const int c  = c0 + ty + 8*i;
        const int hh = c >> 7, dd = c & 127;
        vT[(((size_t)b*H_ + hh)*HD_ + dd)*T_ + t0 + tx] = tile[tx][ty + 8*i];
    }
}

struct GOuts { void* p[3]; int start[3]; int stride[3]; int nseg; };

// ---------------------------------------------------------------------------
// mfma_gemm v2: 128x128 tile, BK=64, DOUBLE-BUFFERED 2-phase schedule.
// C[M,N] = A[M,K] @ BT[N,K]^T.  M%128==0, K%128==0; N handled by ccol<N
// guard; segment starts multiples of 128.
//
// Round-5 rationale: the 8-phase counted-vmcnt port (rounds 3-4) ran at
// ~374 TF — hipcc inserts conservative vmcnt drains before ds_reads that
// may alias outstanding global_load_lds LDS-DMA (same smem array), turning
// counted-vmcnt into drain-per-phase; plus 1-block/CU fill losses. This
// 2-phase form drains vmcnt(0) ONCE per K-tile anyway, so the compiler's
// alias wait is subsumed — robust either way:
//   STG(buf^1, t+1)  -> issue 8 global_load_lds (fire-and-forget)
//   LD(buf) + MFMA   -> staging overlaps a full K-tile of compute
//   vmcnt(0); barrier
// BK=64 halves the drain/barrier frequency vs the old BK=32 kernel.
// LDS 2 x 32KB = 64KB -> 2 blocks/CU (launch_bounds(256,2)).
// XOR slot-swizzle (rows are 128B == 0 mod 32 dwords, mandatory):
//   write: linear dest tid*16; global source 16B-col = (tid&7)^((tid>>3)&7)
//   read:  physical slot = (ks*4+quad) ^ (l16&7)  -> conflict-free b128.
// ---------------------------------------------------------------------------
__global__ __launch_bounds__(256, 2) void mfma_gemm(const bf16* __restrict__ A,
                                                    const bf16* __restrict__ BT,
                                                    GOuts go, int N, int K,
                                                    const int* __restrict__ flag, int cH)
{
    __shared__ __align__(16) char smem[65536];
    const int cf   = cH ? *flag : 0;
    const int tid  = threadIdx.x;
    const int lane = tid & 63;
    const int quad = lane >> 4;
    const int l16  = lane & 15;
    const int w    = tid >> 6;
    const int wm   = w >> 1, wn = w & 1;
    const int bm   = blockIdx.y * 128, bn = blockIdx.x * 128;

    int seg = 0;
    #pragma unroll
    for (int i = 1; i < 3; ++i)
        if (i < go.nseg && bn >= go.start[i]) seg = i;
    void* const dstp   = go.p[seg];
    const int  dstoff  = go.start[seg];
    const int  dstride = go.stride[seg];

    const int nkt = K >> 6;                       // K-tiles of 64 (even: K%128==0)

    // staging: linear LDS dest, inverse-swizzled global source (rule 21)
    const int sR   = tid >> 3;                    // row 0..31 within 32-row group
    const int sCol = ((tid & 7) ^ (sR & 7)) * 8;  // bf16 col: slot ^ (row&7)
    const bf16* gA = A  + (size_t)(bm + sR) * K + sCol;
    const bf16* gB = BT + (size_t)(bn + sR) * K + sCol;
    // ds_read swizzle key = row&7 = l16&7 (rows are i*16+l16, 16==0 mod 8)
    const int rxk  = l16 & 7;
    const int aOff = (wm*64 + l16) * 128;
    const int bOff = 16384 + (wn*64 + l16) * 128;

    f32x4 acc[4][4];
    #pragma unroll
    for (int i = 0; i < 4; ++i)
        #pragma unroll
        for (int j = 0; j < 4; ++j)
            acc[i][j] = (f32x4){0.f, 0.f, 0.f, 0.f};

    s16x8 af[4][2], bf[4][2];

    #define STG(buf, kt) do {                                                    \
        const int ke_ = ((kt) < nkt ? (kt) : nkt-1) * 64;                        \
        _Pragma("unroll")                                                        \
        for (int j_ = 0; j_ < 4; ++j_)                                           \
            __builtin_amdgcn_global_load_lds(                                    \
                (const __attribute__((address_space(1))) unsigned int*)          \
                    (gA + (size_t)(j_*32) * K + ke_),                            \
                (__attribute__((address_space(3))) unsigned int*)                \
                    (smem + (buf)*32768 + j_*4096 + tid*16), 16, 0, 0);          \
        _Pragma("unroll")                                                        \
        for (int j_ = 0; j_ < 4; ++j_)                                           \
            __builtin_amdgcn_global_load_lds(                                    \
                (const __attribute__((address_space(1))) unsigned int*)          \
                    (gB + (size_t)(j_*32) * K + ke_),                            \
                (__attribute__((address_space(3))) unsigned int*)                \
                    (smem + (buf)*32768 + 16384 + j_*4096 + tid*16), 16, 0, 0);  \
    } while (0)

    #define LD(buf) do {                                                         \
        _Pragma("unroll")                                                        \
        for (int i_ = 0; i_ < 4; ++i_)                                           \
            _Pragma("unroll")                                                    \
            for (int ks_ = 0; ks_ < 2; ++ks_)                                    \
                af[i_][ks_] = *(const s16x8*)(smem + (buf)*32768 + aOff          \
                              + i_*2048 + ((((ks_<<2)|quad) ^ rxk) << 4));       \
        _Pragma("unroll")                                                        \
        for (int j_ = 0; j_ < 4; ++j_)                                           \
            _Pragma("unroll")                                                    \
            for (int ks_ = 0; ks_ < 2; ++ks_)                                    \
                bf[j_][ks_] = *(const s16x8*)(smem + (buf)*32768 + bOff          \
                              + j_*2048 + ((((ks_<<2)|quad) ^ rxk) << 4));       \
    } while (0)

    #define MM do {                                                              \
        __builtin_amdgcn_s_setprio(1);                                           \
        _Pragma("unroll")                                                        \
        for (int i_ = 0; i_ < 4; ++i_)                                           \
            _Pragma("unroll")                                                    \
            for (int j_ = 0; j_ < 4; ++j_)                                       \
                _Pragma("unroll")                                                \
                for (int ks_ = 0; ks_ < 2; ++ks_)                                \
                    acc[i_][j_] = __builtin_amdgcn_mfma_f32_16x16x32_bf16(       \
                        af[i_][ks_], bf[j_][ks_], acc[i_][j_], 0, 0, 0);         \
        __builtin_amdgcn_s_setprio(0);                                           \
    } while (0)

    #define DRAIN asm volatile("s_waitcnt vmcnt(0)" ::: "memory");               \
                  __builtin_amdgcn_s_barrier()

    STG(0, 0);
    DRAIN;

    for (int t = 0; t < nkt; t += 2) {
        STG(1, t+1);      // issue-early: overlaps LD+MFMA below
        LD(0);
        MM;
        DRAIN;            // buf1 staged + buf0 consumed by all waves
        STG(0, t+2);      // last iter: clamped duplicate, never read
        LD(1);
        MM;
        DRAIN;
    }

    #undef STG
    #undef LD
    #undef MM
    #undef DRAIN

    #pragma unroll
    for (int i = 0; i < 4; ++i) {
        const int crow = bm + wm*64 + i*16 + quad*4;
        #pragma unroll
        for (int r = 0; r < 4; ++r) {
            #pragma unroll
            for (int j = 0; j < 4; ++j) {
                const int ccol = bn + wn*64 + j*16 + l16;
                if (ccol < N) {
                    const size_t idx = (size_t)(crow + r) * dstride + (ccol - dstoff);
                    if (cf) ((float*)dstp)[idx] = acc[i][j][r];
                    else    ((bf16*)dstp)[idx] = f2b(acc[i][j][r]);
                }
            }
        }
    }
}

// ---------------------------------------------------------------------------
// In-place RMSNorm over rows of X [rows, NPER*256] (internal bf16)
// ---------------------------------------------------------------------------
template<int NPER>
__global__ __launch_bounds__(256) void rms_kernel(bf16* __restrict__ X,
                                                  const void* __restrict__ w,
                                                  const int* __restrict__ flag)
{
    const int wf = *flag;
    const int ncols = NPER * 256;
    __shared__ float red[4];
    const int row = blockIdx.x;
    const int tid = threadIdx.x;
    bf16* xr = X + (size_t)row * ncols;
    float vals[NPER];
    float ss = 0.f;
    #pragma unroll
    for (int i = 0; i < NPER; ++i) {
        float v = b2f(xr[tid + i*256]);
        vals[i] = v; ss += v*v;
    }
    #pragma unroll
    for (int off = 32; off; off >>= 1) ss += __shfl_down(ss, off, 64);
    if ((tid & 63) == 0) red[tid >> 6] = ss;
    __syncthreads();
    const float tot = red[0]+red[1]+red[2]+red[3];
    const float rs  = rsqrtf(tot / (float)ncols + 1e-6f);
    #pragma unroll
    for (int i = 0; i < NPER; ++i) {
        const int c = tid + i*256;
        xr[c] = f2b(vals[i] * rs * ldS(w, c, wf));
    }
}

// ---------------------------------------------------------------------------
// k_pe: in-place RMSNorm over 64 cols + RoPE
// ---------------------------------------------------------------------------
__global__ __launch_bounds__(64) void kpe_rms_rope(bf16* __restrict__ X,
                                                   const void* __restrict__ w,
                                                   const int* __restrict__ flag)
{
    const int wf   = *flag;
    const int row  = blockIdx.x;
    const int t    = row & (T_ - 1);
    const int lane = threadIdx.x;
    bf16* xr = X + (size_t)row * RD_;
    const float v = b2f(xr[lane]);
    float ss = v * v;
    #pragma unroll
    for (int off = 32; off; off >>= 1) ss += __shfl_down(ss, off, 64);
    ss = __shfl(ss, 0, 64);
    const float rs = rsqrtf(ss / 64.f + 1e-6f);
    const float xn = v * rs * ldS(w, lane, wf);
    const int   i  = lane & 31;
    const float freq = powf(10000.f, -(float)(2*i) / 64.f);
    const float ang  = (float)t * freq;
    const float s = sinf(ang), c = cosf(ang);
    const float other = __shfl_xor(xn, 32, 64);
    const float o = (lane < 32) ? (xn * c - other * s) : (other * s + xn * c);
    xr[lane] = f2b(o);
}

// ---------------------------------------------------------------------------
// q_pe RoPE in-place: X [B*T, H*64]
// ---------------------------------------------------------------------------
__global__ __launch_bounds__(256) void qpe_rope(bf16* __restrict__ X)
{
    const int row = blockIdx.x;
    const int t   = row & (T_ - 1);
    bf16* xr = X + (size_t)row * (H_ * RD_);
    const int tid = threadIdx.x;
    #pragma unroll
    for (int pp = 0; pp < 2; ++pp) {
        const int p  = tid + pp * 256;
        const int hh = p >> 5;
        const int i  = p & 31;
        const int i0 = hh * 64 + i;
        const int i1 = i0 + 32;
        const float x1 = b2f(xr[i0]), x2 = b2f(xr[i1]);
        const float freq = powf(10000.f, -(float)(2*i) / 64.f);
        const float ang  = (float)t * freq;
        const float s = sinf(ang), c = cosf(ang);
        xr[i0] = f2b(x1 * c - x2 * s);
        xr[i1] = f2b(x1 * s + x2 * c);
    }
}

// ---------------------------------------------------------------------------
// Flash-style MFMA attention v5 (passing @114.5us, round-2 verified):
// tight LDS + XOR swizzle (48KB, 3 blocks/CU), spill-free softmax.
// ---------------------------------------------------------------------------
__global__ __launch_bounds__(256, 2) void flash_attn(const bf16* __restrict__ qnop,
                                                     const bf16* __restrict__ qpe,
                                                     const bf16* __restrict__ kv,
                                                     const bf16* __restrict__ kpe,
                                                     const bf16* __restrict__ vT,
                                                     bf16* __restrict__ y)
{
    __shared__ __align__(16) short Klds[64 * 192];
    __shared__ __align__(16) short Vt[128 * 64];
    __shared__ __align__(16) short Plds[4][16 * 64];

    const int h   = blockIdx.x;
    const int qt  = 31 - (int)blockIdx.y;          // heavy blocks dispatched first
    const int b   = blockIdx.z;
    const int q0  = qt * 64;
    const int tid = threadIdx.x;
    const int w    = tid >> 6;
    const int lane = tid & 63;
    const int quad = lane >> 4;
    const int l16  = lane & 15;
    const int rk   = l16 & 7;
    const int rkp  = (l16 ^ (l16 >> 3)) & 7;
    const int row0 = q0 + w * 16;
    const size_t bT = (size_t)b * T_;
    const int bh  = b * H_ + h;

    const int kR = tid >> 4, kS = tid & 15;
    const int pR = tid >> 3, pS = tid & 7;
    const int vD = tid >> 3, vS = tid & 7;

    const bf16* gK = kv  + (bT + kR) * (H_*256) + h*128 + kS*8;
    const bf16* gP = kpe + (bT + pR) * RD_ + pS*8;
    const bf16* gV = vT  + ((size_t)bh*HD_ + vD) * T_ + vS*8;

    short* const wK = &Klds[kR*192 + ((kS ^ (kR & 7)) << 3)];
    short* const wP = &Klds[pR*192 + 128 + ((pS ^ (pR & 7)) << 3)];
    short* const wV = &Vt[vD*64 + ((vS ^ (vD & 7)) << 3)];

    s16x8 aq[6];
    {
        const size_t r = bT + row0 + l16;
        const bf16* qn = qnop + r * (H_*128) + h*128 + quad*8;
        #pragma unroll
        for (int kk = 0; kk < 4; ++kk) aq[kk] = *(const s16x8*)(qn + kk*32);
        const bf16* qp = qpe + r * (H_*64) + h*64 + quad*8;
        aq[4] = *(const s16x8*)(qp);
        aq[5] = *(const s16x8*)(qp + 32);
    }

    f32x4 o[8];
    #pragma unroll
    for (int i = 0; i < 8; ++i) o[i] = (f32x4){0.f,0.f,0.f,0.f};
    float m_run[4] = {-1e30f,-1e30f,-1e30f,-1e30f};
    float l_run[4] = {0.f,0.f,0.f,0.f};

    uint4 k0, k1, k2, k3, p0, p1, v0, v1, v2, v3;
    #define PF(J0) do {                                                     \
        const bf16* a_ = gK + (size_t)(J0) * (H_*256);                      \
        k0 = *(const uint4*)(a_);                                           \
        k1 = *(const uint4*)(a_ + 16*(H_*256));                             \
        k2 = *(const uint4*)(a_ + 32*(H_*256));                             \
        k3 = *(const uint4*)(a_ + 48*(H_*256));                             \
        const bf16* p_ = gP + (size_t)(J0) * RD_;                           \
        p0 = *(const uint4*)(p_);                                           \
        p1 = *(const uint4*)(p_ + 32*RD_);                                  \
        const bf16* v_ = gV + (J0);                                         \
        v0 = *(const uint4*)(v_);                                           \
        v1 = *(const uint4*)(v_ + 32*T_);                                   \
        v2 = *(const uint4*)(v_ + 64*T_);                                   \
        v3 = *(const uint4*)(v_ + 96*T_);                                   \
    } while (0)

    PF(0);

    const int ntiles = qt + 1;
    for (int it = 0; it < ntiles; ++it) {
        const int j0 = it * 64;
        asm volatile("s_waitcnt lgkmcnt(0)\n\ts_barrier" ::: "memory");

        *(uint4*)(wK)          = k0;
        *(uint4*)(wK + 16*192) = k1;
        *(uint4*)(wK + 32*192) = k2;
        *(uint4*)(wK + 48*192) = k3;
        *(uint4*)(wP)          = p0;
        *(uint4*)(wP + 32*192) = p1;
        *(uint4*)(wV)          = v0;
        *(uint4*)(wV + 32*64)  = v1;
        *(uint4*)(wV + 64*64)  = v2;
        *(uint4*)(wV + 96*64)  = v3;

        if (it + 1 < ntiles) PF(j0 + 64);

        asm volatile("s_waitcnt lgkmcnt(0)\n\ts_barrier" ::: "memory");

        if (j0 <= row0 + 15) {
            const bool needmask = (j0 + 63 > row0);
            f32x4 s[4];
            #pragma unroll
            for (int nsub = 0; nsub < 4; ++nsub) {
                f32x4 acc = (f32x4){0.f,0.f,0.f,0.f};
                #pragma unroll
                for (int kk = 0; kk < 6; ++kk) {
                    const s16x8 bk = *(const s16x8*)&Klds[(nsub*16 + l16)*192
                                        + ((((kk << 2) | quad) ^ rk) << 3)];
                    acc = __builtin_amdgcn_mfma_f32_16x16x32_bf16(aq[kk], bk, acc, 0, 0, 0);
                }
                #pragma unroll
                for (int reg = 0; reg < 4; ++reg) acc[reg] *= SCALE_;
                s[nsub] = acc;
            }
            if (needmask) {
                #pragma unroll
                for (int nsub = 0; nsub < 4; ++nsub)
                    #pragma unroll
                    for (int reg = 0; reg < 4; ++reg) {
                        const int col = j0 + nsub*16 + l16;
                        const int row = row0 + quad*4 + reg;
                        if (col > row) s[nsub][reg] = -1e30f;
                    }
            }
            float mt[4], alpha[4], rs[4];
            #pragma unroll
            for (int reg = 0; reg < 4; ++reg)
                mt[reg] = fmaxf(fmaxf(s[0][reg], s[1][reg]), fmaxf(s[2][reg], s[3][reg]));
            #pragma unroll
            for (int d = 1; d < 16; d <<= 1)
                #pragma unroll
                for (int reg = 0; reg < 4; ++reg)
                    mt[reg] = fmaxf(mt[reg], __shfl_xor(mt[reg], d, 64));
            #pragma unroll
            for (int reg = 0; reg < 4; ++reg) {
                const float mnew = fmaxf(m_run[reg], mt[reg]);
                alpha[reg] = __expf(m_run[reg] - mnew);
                m_run[reg] = mnew;
                rs[reg] = 0.f;
            }
            #pragma unroll
            for (int nsub = 0; nsub < 4; ++nsub)
                #pragma unroll
                for (int reg = 0; reg < 4; ++reg) {
                    const float p = __expf(s[nsub][reg] - m_run[reg]);
                    s[nsub][reg] = p;
                    rs[reg] += p;
                }
            #pragma unroll
            for (int d = 1; d < 16; d <<= 1)
                #pragma unroll
                for (int reg = 0; reg < 4; ++reg)
                    rs[reg] += __shfl_xor(rs[reg], d, 64);
            #pragma unroll
            for (int reg = 0; reg < 4; ++reg)
                l_run[reg] = l_run[reg] * alpha[reg] + rs[reg];

            #pragma unroll
            for (int nsub = 0; nsub < 4; ++nsub)
                #pragma unroll
                for (int reg = 0; reg < 4; ++reg) {
                    const bf16 pv = f2b(s[nsub][reg]);
                    const int prow = (quad << 2) + reg;
                    const int pk   = (prow ^ (prow >> 3)) & 7;
                    const int pby  = ((nsub << 5) + (l16 << 1)) ^ (pk << 4);
                    Plds[w][prow*64 + (pby >> 1)] = *(const short*)&pv;
                }
            #pragma unroll
            for (int n2 = 0; n2 < 8; ++n2)
                #pragma unroll
                for (int reg = 0; reg < 4; ++reg)
                    o[n2][reg] *= alpha[reg];

            const s16x8 ap0 = *(const s16x8*)&Plds[w][l16*64 + (((quad    ) ^ rkp) << 3)];
            const s16x8 ap1 = *(const s16x8*)&Plds[w][l16*64 + (((quad | 4) ^ rkp) << 3)];
            #pragma unroll
            for (int n2 = 0; n2 < 8; ++n2) {
                const s16x8 bv0 = *(const s16x8*)&Vt[(n2*16 + l16)*64 + (((quad    ) ^ rk) << 3)];
                const s16x8 bv1 = *(const s16x8*)&Vt[(n2*16 + l16)*64 + (((quad | 4) ^ rk) << 3)];
                o[n2] = __builtin_amdgcn_mfma_f32_16x16x32_bf16(ap0, bv0, o[n2], 0, 0, 0);
                o[n2] = __builtin_amdgcn_mfma_f32_16x16x32_bf16(ap1, bv1, o[n2], 0, 0, 0);
            }
        }
    }
    #undef PF

    #pragma unroll
    for (int reg = 0; reg < 4; ++reg) {
        const float inv = 1.f / l_run[reg];
        const size_t r = bT + row0 + quad*4 + reg;
        bf16* yr = y + r * (H_*128) + h*128 + l16;
        #pragma unroll
        for (int n2 = 0; n2 < 8; ++n2)
            yr[n2*16] = f2b(o[n2][reg] * inv);
    }
}

// ---------------------------------------------------------------------------
extern "C" void kernel_launch(void* const* d_in, const int* in_sizes, int n_in,
                              void* d_out, int out_size, void* d_ws, size_t ws_size,
                              hipStream_t stream)
{
    const void* x         = d_in[0];
    const void* Wq_down   = d_in[1];
    const void* q_norm_w  = d_in[2];
    const void* Wq_up     = d_in[3];
    const void* Wq_pe     = d_in[4];
    const void* Wkv_down  = d_in[5];
    const void* kv_norm_w = d_in[6];
    const void* Wkv_up    = d_in[7];
    const void* Wk_pe     = d_in[8];
    const void* kpe_nw    = d_in[9];
    const void* Wo        = d_in[10];

    char* ws = (char*)d_ws;
    int*  flag = (int*)(ws + 0);
    bf16* xb   = (bf16*)(ws + 256);        // [4096,2048] — dead after x-GEMM; reused as vT
    bf16* cQ   = (bf16*)(ws + 16777472);   // [4096,1536] — dead after q-GEMM; reused as P3/P4
    bf16* cKV  = (bf16*)(ws + 29360384);   // [4096, 512]
    bf16* kpeb = (bf16*)(ws + 33554688);   // [4096,  64]
    bf16* qnop = (bf16*)(ws + 34078976);   // [4096,2048]
    bf16* qpeb = (bf16*)(ws + 50856192);   // [4096,1024]
    bf16* kvb  = (bf16*)(ws + 59244800);   // [4096,4096] — written late; holds P1/P2 early
    bf16* yb   = (bf16*)(ws + 92799232);   // [4096,2048]  (end 109,576,448)

    // weight arenas (lifetime-safe overlays):
    bf16* P1 = kvb;                            // [2176][2048] x-weights^T (8.9 MB)
    bf16* P2 = (bf16*)((char*)kvb + 8912896);  // [3072][1536] q-weights^T (9.4 MB)
    bf16* P3 = cQ;                             // [4096][512]  Wkv_up^T    (4.2 MB)
    bf16* P4 = (bf16*)((char*)cQ + 4194304);   // [2048][2048] Wo^T        (8.4 MB)
    bf16* vT = xb;                             // [B*H][128][2048] V^T

    const dim3 blk(256);

    detect_kernel<<<1, dim3(64), 0, stream>>>((const unsigned short*)x, flag);
    convert_kernel<<<(B_*T_*C_)/(256*8), blk, 0, stream>>>(x, xb, B_*T_*C_, flag);

    // ---- batched transpose #1: x-path + q-path weights ----
    {
        TBatch tb;
        tb.d[0] = { Wq_down,  P1,               C_,  QLR_,     0, QLR_/32 };    // 3072 blks
        tb.d[1] = { Wkv_down, P1 + 1536*2048,   C_,  KLR_,  3072, KLR_/32 };    // 1024
        tb.d[2] = { Wk_pe,    P1 + 2048*2048,   C_,  RD_,   4096, RD_/32  };    //  128
        tb.d[3] = { Wq_up,    P2,               QLR_, 2048, 4224, 2048/32 };    // 3072
        tb.d[4] = { Wq_pe,    P2 + 2048*1536,   QLR_, 1024, 7296, 1024/32 };    // 1536
        tb.nseg = 5;
        transpose_batch<<<8832, blk, 0, stream>>>(tb, flag);
    }

    // ---- fused x-projection GEMM: x @ [Wq_down | Wkv_down | Wk_pe] ----
    {
        GOuts go; go.nseg = 3;
        go.p[0]=cQ;   go.start[0]=0;    go.stride[0]=QLR_;
        go.p[1]=cKV;  go.start[1]=1536; go.stride[1]=KLR_;
        go.p[2]=kpeb; go.start[2]=2048; go.stride[2]=RD_;
        mfma_gemm<<<dim3(17, 32), blk, 0, stream>>>(xb, P1, go, 2112, C_, flag, 0);
    }
    rms_kernel<6><<<B_*T_, blk, 0, stream>>>(cQ, q_norm_w, flag);
    rms_kernel<2><<<B_*T_, blk, 0, stream>>>(cKV, kv_norm_w, flag);
    kpe_rms_rope<<<B_*T_, dim3(64), 0, stream>>>(kpeb, kpe_nw, flag);

    // ---- fused q-projection GEMM: cQ @ [Wq_up | Wq_pe] ----
    {
        GOuts go; go.nseg = 2;
        go.p[0]=qnop; go.start[0]=0;    go.stride[0]=H_*HD_;
        go.p[1]=qpeb; go.start[1]=2048; go.stride[1]=H_*RD_;
        go.p[2]=nullptr; go.start[2]=0; go.stride[2]=0;
        mfma_gemm<<<dim3(24, 32), blk, 0, stream>>>(cQ, P2, go, 3072, QLR_, flag, 0);
    }
    qpe_rope<<<B_*T_, blk, 0, stream>>>(qpeb);

    // ---- batched transpose #2: Wkv_up, Wo (cQ now dead) ----
    {
        TBatch tb;
        tb.d[0] = { Wkv_up, P3, KLR_, H_*2*HD_,    0, (H_*2*HD_)/32 };  // 2048 blks
        tb.d[1] = { Wo,     P4, H_*HD_, C_,     2048, C_/32 };          // 4096
        tb.d[2] = tb.d[1]; tb.d[3] = tb.d[1]; tb.d[4] = tb.d[1];
        tb.nseg = 2;
        transpose_batch<<<6144, blk, 0, stream>>>(tb, flag);
    }

    // ---- kv up-projection, then V transpose (xb dead) ----
    {
        GOuts go; go.nseg = 1;
        go.p[0]=kvb; go.start[0]=0; go.stride[0]=H_*2*HD_;
        go.p[1]=nullptr; go.start[1]=0; go.stride[1]=0;
        go.p[2]=nullptr; go.start[2]=0; go.stride[2]=0;
        mfma_gemm<<<dim3(32, 32), blk, 0, stream>>>(cKV, P3, go, H_*2*HD_, KLR_, flag, 0);
    }
    transpose_v_kernel<<<dim3((H_*HD_)/32, (B_*T_)/32), blk, 0, stream>>>(kvb, vT);

    // ---- attention ----
    flash_attn<<<dim3(H_, T_/64, B_), blk, 0, stream>>>(qnop, qpeb, kvb, kpeb, vT, yb);

    // ---- output projection (dtype of d_out per flag) ----
    {
        GOuts go; go.nseg = 1;
        go.p[0]=d_out; go.start[0]=0; go.stride[0]=C_;
        go.p[1]=nullptr; go.start[1]=0; go.stride[1]=0;
        go.p[2]=nullptr; go.start[2]=0; go.stride[2]=0;
        mfma_gemm<<<dim3(C_/128, 32), blk, 0, stream>>>(yb, P4, go, C_, H_*HD_, flag, 1);
    }
}